// Round 4
// baseline (6236.450 us; speedup 1.0000x reference)
//
#include <hip/hip_runtime.h>
#include <hip/hip_fp16.h>

#define SEQ  1000
#define IDIM 900
#define H    4096

#define NBLK 128   // recurrent blocks; each owns 32 rows
// LDS for esn_recurrent: s2 : uint[2][2048] fp16-pair s[t], double-buffered
#define LDS_BYTES 16384

typedef _Float16 h2_t __attribute__((ext_vector_type(2)));

__device__ __forceinline__ float fdot2(unsigned a, unsigned b, float c) {
#if __has_builtin(__builtin_amdgcn_fdot2)
    return __builtin_amdgcn_fdot2(__builtin_bit_cast(h2_t, a),
                                  __builtin_bit_cast(h2_t, b), c, false);
#else
    h2_t ha = __builtin_bit_cast(h2_t, a);
    h2_t hb = __builtin_bit_cast(h2_t, b);
    return c + (float)ha.x * (float)hb.x + (float)ha.y * (float)hb.y;
#endif
}

__device__ __forceinline__ float tanh_fast(float x) {
    float ax = __builtin_fabsf(x);
    float e  = __expf(-2.0f * ax);
    float t  = (1.0f - e) / (1.0f + e);
    return __builtin_copysignf(t, x);
}

// Bank swizzle on s2 dword indices: XOR bits [4:2] with bits [7:5].
// Writer (b64 at d=2*tid) and reader (b128 at d=32*lane + 4*chunk) both
// stay aligned; every 16-lane subgroup covers each bank exactly 2x -> free.
__device__ __forceinline__ int swz2(int d) { return d ^ (((d >> 5) & 7) << 2); }

__device__ __forceinline__ uint4 pack8(float4 f0, float4 f1) {
    __half2 p; uint4 u;
    p = __floats2half2_rn(f0.x, f0.y); u.x = *(unsigned*)&p;
    p = __floats2half2_rn(f0.z, f0.w); u.y = *(unsigned*)&p;
    p = __floats2half2_rn(f1.x, f1.y); u.z = *(unsigned*)&p;
    p = __floats2half2_rn(f1.z, f1.w); u.w = *(unsigned*)&p;
    return u;
}

// ---------------------------------------------------------------------------
// Persistent recurrent kernel, round-11: WAVE-OWNS-ROW-PAIR.
// 128 blocks x 1024 threads. Block Bk owns rows [32Bk,+32); wave w owns the
// complete row pair {32Bk+2w, +1} across all 4096 cols (64 cols/lane, W_hh
// as 64 fp16-pair VGPRs). After 64 fdot2/lane, a parity-merged 6-shuffle
// butterfly leaves even lanes = full row-2w sum, odd lanes = row-2w+1 ->
// lanes 0/1 tanh + store states, lane 0 packs half2 and publishes the wave's
// ONE tagged word straight from registers. vs round-9: barrier B, redf, and
// the wave0-serial finalize are GONE (1 barrier/step), publish is spread
// over 16 independent waves, block count halves (poll traffic 4->2 MB/iter,
// producer-max over 128 not 256 blocks).
// Protocol (proven, unchanged invariants): part = 4 slots x 2048 tagged
// words {u32 tag=t+2, 2 x fp16}; word k covers rows 2k,2k+1 (block k>>4,
// wave k&15); thread polls words 2tid,2tid+1 of slot t&3 for tag t+1 and
// scatters payload into swizzled s2[t&1]. Slot safety: publishing tag t+2
// into slot (t+1)&3 overwrites tag t-2, consumed by all blocks before any
// block could publish tag t+1 (NBUF=4 dependency distance, as before).
// s2 double-buffer + single barrier safety: for a wave to write s2[(t+1)&1]
// it passed step-t+1's poll => all blocks published s[t+1] => every wave of
// this block passed barrier A of step t+1 => finished reading s2[t&1].
// ---------------------------------------------------------------------------
__global__ __launch_bounds__(1024, 4) void esn_recurrent(
    const float* __restrict__ Whh,            // H*H row-major fp32
    const float* __restrict__ pre_in,         // SEQ*H = X @ W_ih^T  (ws)
    float*       __restrict__ states,         // SEQ*H (inside d_out)
    unsigned long long* __restrict__ part)    // 4*2048 tagged words (d_out scratch)
{
    extern __shared__ char smem[];
    unsigned* s2 = (unsigned*)smem;                 // [2][2048] swizzled

    const int Bk  = blockIdx.x;        // owns rows [32Bk, +32)
    const int tid = threadIdx.x;
    const int w   = tid >> 6;          // 0..15, owns rows {2w, 2w+1} of my 32
    const int l   = tid & 63;

    // ---- prologue: wave 0 publishes s[0] for all 32 rows (gates others) ----
    if (w == 0) {
        float s0 = 0.f;
        if (l < 32) {
            s0 = tanh_fast(pre_in[(Bk << 5) + l]);
            states[(Bk << 5) + l] = s0;
        }
        float a = __shfl(s0, l << 1);
        float b = __shfl(s0, (l << 1) + 1);
        if (l < 16) {
            __half2 p = __floats2half2_rn(a, b);
            unsigned long long wrd = (1ull << 32)
                                   | (unsigned long long)(*(unsigned*)&p);
            __hip_atomic_store(part + (Bk << 4) + l, wrd,
                               __ATOMIC_RELAXED, __HIP_MEMORY_SCOPE_AGENT);
        }
    }

    // ---- load my row pair of W_hh into registers (fp16 pairs, once) ----
    // Latency overlaps the first poll spin.
    const int r0 = (Bk << 5) + (w << 1);   // global row of acc0
    uint4 w0[8], w1[8];
    {
        const float* p0 = Whh + (size_t)r0 * H + (l << 6);
        const float* p1 = p0 + H;
        #pragma unroll
        for (int k = 0; k < 8; ++k) {
            const float4* q0 = (const float4*)(p0 + (k << 3));
            const float4* q1 = (const float4*)(p1 + (k << 3));
            w0[k] = pack8(q0[0], q0[1]);
            w1[k] = pack8(q1[0], q1[1]);
        }
    }

    for (int t = 0; t < SEQ - 1; ++t) {
        // prefetch pre_in[t+1] for my 2 rows (issued before the poll)
        float pv = 0.f;
        if (l < 2) pv = pre_in[(size_t)(t + 1) * H + r0 + l];

        // ---- A. poll s[t] (slot t&3, tag t+1); thread owns words 2tid,2tid+1 ----
        {
            const unsigned long long* pb = part + ((size_t)(t & 3) << 11) + (tid << 1);
            const unsigned want = (unsigned)(t + 1);
            unsigned long long v0, v1;
            for (;;) {
                v0 = __hip_atomic_load(pb,     __ATOMIC_RELAXED, __HIP_MEMORY_SCOPE_AGENT);
                v1 = __hip_atomic_load(pb + 1, __ATOMIC_RELAXED, __HIP_MEMORY_SCOPE_AGENT);
                if ((unsigned)(v0 >> 32) == want && (unsigned)(v1 >> 32) == want) break;
                __builtin_amdgcn_s_sleep(1);
            }
            uint2 wv; wv.x = (unsigned)v0; wv.y = (unsigned)v1;
            *(uint2*)(s2 + ((t & 1) << 11) + swz2(tid << 1)) = wv;
        }
        __syncthreads();   // the ONLY barrier per step

        // ---- B. rows {r0, r0+1} x cols [64l, +64): 64 fdot2/lane ----
        const unsigned* sb = s2 + ((t & 1) << 11);
        float a0 = 0.f, b0 = 0.f, a1 = 0.f, b1 = 0.f;
        #pragma unroll
        for (int k = 0; k < 8; k += 2) {
            uint4 se = *(const uint4*)(sb + swz2((l << 5) + (k << 2)));
            uint4 so = *(const uint4*)(sb + swz2((l << 5) + ((k + 1) << 2)));
            a0 = fdot2(w0[k].x, se.x, a0);     a0 = fdot2(w0[k].y, se.y, a0);
            a0 = fdot2(w0[k].z, se.z, a0);     a0 = fdot2(w0[k].w, se.w, a0);
            b0 = fdot2(w0[k+1].x, so.x, b0);   b0 = fdot2(w0[k+1].y, so.y, b0);
            b0 = fdot2(w0[k+1].z, so.z, b0);   b0 = fdot2(w0[k+1].w, so.w, b0);
            a1 = fdot2(w1[k].x, se.x, a1);     a1 = fdot2(w1[k].y, se.y, a1);
            a1 = fdot2(w1[k].z, se.z, a1);     a1 = fdot2(w1[k].w, se.w, a1);
            b1 = fdot2(w1[k+1].x, so.x, b1);   b1 = fdot2(w1[k+1].y, so.y, b1);
            b1 = fdot2(w1[k+1].z, so.z, b1);   b1 = fdot2(w1[k+1].w, so.w, b1);
        }
        float r0s = a0 + b0;   // row r0 partial over my 64 cols
        float r1s = a1 + b1;   // row r0+1 partial

        // ---- parity-merged butterfly: 6 shuffles ----
        float keep = (l & 1) ? r1s : r0s;
        float send = (l & 1) ? r0s : r1s;
        keep += __shfl_xor(send, 1);
        keep += __shfl_xor(keep, 2);
        keep += __shfl_xor(keep, 4);
        keep += __shfl_xor(keep, 8);
        keep += __shfl_xor(keep, 16);
        keep += __shfl_xor(keep, 32);
        // even lanes: full row r0 sum; odd lanes: full row r0+1 sum

        // ---- C. tail, zero barriers: tanh + store + publish from regs ----
        float sf = tanh_fast(keep + pv);       // meaningful in lanes 0,1
        if (l < 2) states[(size_t)(t + 1) * H + r0 + l] = sf;
        float other = __shfl(sf, 1);
        if (l == 0) {
            __half2 p = __floats2half2_rn(sf, other);
            unsigned long long wrd = ((unsigned long long)(unsigned)(t + 2) << 32)
                                   | (unsigned long long)(*(unsigned*)&p);
            __hip_atomic_store(part + ((size_t)((t + 1) & 3) << 11) + (Bk << 4) + w,
                               wrd, __ATOMIC_RELAXED, __HIP_MEMORY_SCOPE_AGENT);
        }
    }
}

// ---------------------------------------------------------------------------
// Generic fp32 tiled GEMM:  C[MxN] = A[MxK] * B[NxK]^T   (both row-major)
// mode 0: A plain (lda). mode 1: virtual ext row t: [1, X[t], S[t]].
// ---------------------------------------------------------------------------
#define BM 64
#define BN 64
#define BK 32

__global__ __launch_bounds__(256) void gemm_abt(
    const float* __restrict__ A, int lda,
    const float* __restrict__ B, int ldb,
    float*       __restrict__ C, int ldc,
    int Mdim, int N, int K, int mode,
    const float* __restrict__ X, const float* __restrict__ S)
{
    __shared__ __align__(16) float As[BK][BM + 4];
    __shared__ __align__(16) float Bs[BK][BN + 4];

    const int tid = threadIdx.x;
    const int n0  = blockIdx.x * BN;
    const int m0  = blockIdx.y * BM;
    const int tx  = tid & 15;
    const int ty  = tid >> 4;

    float c[4][4] = {};

    for (int k0 = 0; k0 < K; k0 += BK) {
        #pragma unroll
        for (int p = 0; p < 8; ++p) {
            const int idx = tid + p * 256;
            const int mm  = idx >> 5;
            const int kk  = idx & 31;
            const int gk  = k0 + kk;

            float av = 0.f;
            const int gm = m0 + mm;
            if (gm < Mdim && gk < K) {
                if (mode == 0) {
                    av = A[(size_t)gm * lda + gk];
                } else {
                    if (gk == 0)          av = 1.0f;
                    else if (gk <= IDIM)  av = X[(size_t)gm * IDIM + (gk - 1)];
                    else                  av = S[(size_t)gm * H + (gk - 1 - IDIM)];
                }
            }
            As[kk][mm] = av;

            float bv = 0.f;
            const int gn = n0 + mm;
            if (gn < N && gk < K) bv = B[(size_t)gn * ldb + gk];
            Bs[kk][mm] = bv;
        }
        __syncthreads();

        #pragma unroll
        for (int kk = 0; kk < BK; ++kk) {
            float4 a = *(const float4*)&As[kk][ty * 4];
            float4 b = *(const float4*)&Bs[kk][tx * 4];
            float av[4] = {a.x, a.y, a.z, a.w};
            float bv[4] = {b.x, b.y, b.z, b.w};
            #pragma unroll
            for (int i = 0; i < 4; ++i)
                #pragma unroll
                for (int j = 0; j < 4; ++j)
                    c[i][j] += av[i] * bv[j];
        }
        __syncthreads();
    }

    #pragma unroll
    for (int i = 0; i < 4; ++i) {
        const int gm = m0 + ty * 4 + i;
        if (gm >= Mdim) continue;
        #pragma unroll
        for (int j = 0; j < 4; ++j) {
            const int gn = n0 + tx * 4 + j;
            if (gn < N) C[(size_t)gm * ldc + gn] = c[i][j];
        }
    }
}

// ---------------------------------------------------------------------------
// Split-K GEMM for phase 2 (mode-1 virtual A only):
//   Cp[z][M][N] partial over K-slice z. Grid (N/BN, M/BM, 4).
// ---------------------------------------------------------------------------
#define KSLICE 1280   // 40 tiles of 32; slice 3 gets the 1157-tail

__global__ __launch_bounds__(256) void gemm_splitk(
    const float* __restrict__ Bw, int ldb,
    float*       __restrict__ Cp,            // 4 partials, stride M*N
    int Mdim, int N, int K,
    const float* __restrict__ X, const float* __restrict__ S)
{
    __shared__ __align__(16) float As[BK][BM + 4];
    __shared__ __align__(16) float Bs[BK][BN + 4];

    const int tid = threadIdx.x;
    const int n0  = blockIdx.x * BN;
    const int m0  = blockIdx.y * BM;
    const int z   = blockIdx.z;
    const int tx  = tid & 15;
    const int ty  = tid >> 4;

    const int kbeg = z * KSLICE;
    const int kend = min(K, kbeg + KSLICE);

    float c[4][4] = {};

    for (int k0 = kbeg; k0 < kend; k0 += BK) {
        const bool pureS = (k0 >= IDIM + 1) && (k0 + BK <= kend);
        const bool pureX = (k0 > 0) && (k0 + BK <= IDIM + 1);
        #pragma unroll
        for (int p = 0; p < 8; ++p) {
            const int idx = tid + p * 256;
            const int mm  = idx >> 5;
            const int kk  = idx & 31;
            const int gk  = k0 + kk;
            const int gm  = m0 + mm;

            float av = 0.f;
            if (gm < Mdim) {
                if (pureS)      av = S[(size_t)gm * H + (gk - 1 - IDIM)];
                else if (pureX) av = X[(size_t)gm * IDIM + (gk - 1)];
                else if (gk < kend) {
                    if (gk == 0)          av = 1.0f;
                    else if (gk <= IDIM)  av = X[(size_t)gm * IDIM + (gk - 1)];
                    else                  av = S[(size_t)gm * H + (gk - 1 - IDIM)];
                }
            }
            As[kk][mm] = av;

            float bv = 0.f;
            const int gn = n0 + mm;
            if (gn < N && gk < kend) bv = Bw[(size_t)gn * ldb + gk];
            Bs[kk][mm] = bv;
        }
        __syncthreads();

        #pragma unroll
        for (int kk = 0; kk < BK; ++kk) {
            float4 a = *(const float4*)&As[kk][ty * 4];
            float4 b = *(const float4*)&Bs[kk][tx * 4];
            float av[4] = {a.x, a.y, a.z, a.w};
            float bv[4] = {b.x, b.y, b.z, b.w};
            #pragma unroll
            for (int i = 0; i < 4; ++i)
                #pragma unroll
                for (int j = 0; j < 4; ++j)
                    c[i][j] += av[i] * bv[j];
        }
        __syncthreads();
    }

    float* Cz = Cp + (size_t)z * ((size_t)SEQ * IDIM);
    #pragma unroll
    for (int i = 0; i < 4; ++i) {
        const int gm = m0 + ty * 4 + i;
        if (gm >= Mdim) continue;
        #pragma unroll
        for (int j = 0; j < 4; ++j) {
            const int gn = n0 + tx * 4 + j;
            if (gn < N) Cz[(size_t)gm * N + gn] = c[i][j];
        }
    }
}

// out[i] = sum of 4 split-K partials (SEQ*IDIM floats, /4 exact)
__global__ __launch_bounds__(256) void reduce4(
    const float4* __restrict__ p, float4* __restrict__ o, int n4)
{
    const size_t stride = (size_t)SEQ * IDIM / 4;
    for (int i = blockIdx.x * 256 + threadIdx.x; i < n4; i += gridDim.x * 256) {
        float4 a = p[i];
        float4 b = p[i + stride];
        float4 c = p[i + 2 * stride];
        float4 d = p[i + 3 * stride];
        float4 r;
        r.x = a.x + b.x + c.x + d.x;
        r.y = a.y + b.y + c.y + d.y;
        r.z = a.z + b.z + c.z + d.z;
        r.w = a.w + b.w + c.w + d.w;
        o[i] = r;
    }
}

// ---------------------------------------------------------------------------
// Launcher
// ---------------------------------------------------------------------------
extern "C" void kernel_launch(void* const* d_in, const int* in_sizes, int n_in,
                              void* d_out, int out_size, void* d_ws, size_t ws_size,
                              hipStream_t stream) {
    const float* inputs = (const float*)d_in[0];
    // d_in[1] = initial state (zeros) — folded out
    const float* W_ih   = (const float*)d_in[2];
    const float* W_hh   = (const float*)d_in[3];
    const float* W_out  = (const float*)d_in[4];

    float* out    = (float*)d_out;                 // SEQ*IDIM
    float* states = out + (size_t)SEQ * IDIM;      // SEQ*H

    float* pre_in = (float*)d_ws;                  // SEQ*H fp32 (16.4 MB)
    float* cpart  = pre_in + (size_t)SEQ * H;      // 4 * SEQ*IDIM fp32 (14.4 MB)

    const size_t ws_needed = ((size_t)SEQ * H + 4ull * SEQ * IDIM) * sizeof(float);
    const bool   use_splitk = (ws_size >= ws_needed);

    // Tagged s-broadcast scratch in the outputs region of d_out (overwritten
    // by phase 2): 4 slots * 2048 words * 8 B = 64 KB. Harness 0xAA poison
    // gives tag 0xAAAAAAAA, never equal to a live tag (1..1000).
    unsigned long long* part = (unsigned long long*)out;

    (void)hipFuncSetAttribute((const void*)esn_recurrent,
                              hipFuncAttributeMaxDynamicSharedMemorySize,
                              LDS_BYTES);

    // Phase 0: pre_in[t][r] = sum_i X[t][i] * W_ih[r][i]
    gemm_abt<<<dim3(H / BN, (SEQ + BM - 1) / BM), 256, 0, stream>>>(
        inputs, IDIM, W_ih, IDIM, pre_in, H, SEQ, H, IDIM, 0, nullptr, nullptr);

    // Phase 1: persistent sequential recurrence (128 blocks x 1024 threads)
    {
        const float* whh_p = W_hh;
        const float* pin_p = pre_in;
        float* st_p = states;
        unsigned long long* part_p = part;
        void* args[] = { (void*)&whh_p, (void*)&pin_p, (void*)&st_p, (void*)&part_p };
        hipLaunchCooperativeKernel((const void*)esn_recurrent,
                                   dim3(NBLK), dim3(1024), args, LDS_BYTES, stream);
    }

    // Phase 2: outputs[t][i] = sum_k ext[t][k] * W_out[i][k]
    if (use_splitk) {
        gemm_splitk<<<dim3((IDIM + BN - 1) / BN, (SEQ + BM - 1) / BM, 4),
                      256, 0, stream>>>(
            W_out, 1 + IDIM + H, cpart, SEQ, IDIM, 1 + IDIM + H, inputs, states);
        const int n4 = SEQ * IDIM / 4;
        reduce4<<<dim3(880), 256, 0, stream>>>(
            (const float4*)cpart, (float4*)out, n4);
    } else {
        gemm_abt<<<dim3((IDIM + BN - 1) / BN, (SEQ + BM - 1) / BM), 256, 0, stream>>>(
            nullptr, 0, W_out, 1 + IDIM + H, out, IDIM,
            SEQ, IDIM, 1 + IDIM + H, 1, inputs, states);
    }
}

// Round 5
// 6010.104 us; speedup vs baseline: 1.0377x; 1.0377x over previous
//
#include <hip/hip_runtime.h>
#include <hip/hip_fp16.h>

#define SEQ  1000
#define IDIM 900
#define H    4096

// LDS carve-up for esn_recurrent (W_hh lives in REGISTERS):
//   s2   : uint[2][2048]  s[t] fp16 pairs, double-buffered = 16384 B
//   redf : float[16][4]   per-(row, colquad 1..3) partials =   256 B
#define LDS_BYTES (16384 + 256)

typedef _Float16 h2_t __attribute__((ext_vector_type(2)));

__device__ __forceinline__ float fdot2(unsigned a, unsigned b, float c) {
#if __has_builtin(__builtin_amdgcn_fdot2)
    return __builtin_amdgcn_fdot2(__builtin_bit_cast(h2_t, a),
                                  __builtin_bit_cast(h2_t, b), c, false);
#else
    h2_t ha = __builtin_bit_cast(h2_t, a);
    h2_t hb = __builtin_bit_cast(h2_t, b);
    return c + (float)ha.x * (float)hb.x + (float)ha.y * (float)hb.y;
#endif
}

__device__ __forceinline__ float tanh_fast(float x) {
    float ax = __builtin_fabsf(x);
    float e  = __expf(-2.0f * ax);
    float t  = (1.0f - e) / (1.0f + e);
    return __builtin_copysignf(t, x);
}

// Bank swizzle on s2 dword indices: XOR bits [4:2] with bits [7:5].
__device__ __forceinline__ int swz2(int d) { return d ^ (((d >> 5) & 7) << 2); }

__device__ __forceinline__ uint4 pack8(float4 f0, float4 f1) {
    __half2 p; uint4 u;
    p = __floats2half2_rn(f0.x, f0.y); u.x = *(unsigned*)&p;
    p = __floats2half2_rn(f0.z, f0.w); u.y = *(unsigned*)&p;
    p = __floats2half2_rn(f1.x, f1.y); u.z = *(unsigned*)&p;
    p = __floats2half2_rn(f1.z, f1.w); u.w = *(unsigned*)&p;
    return u;
}

// ---------------------------------------------------------------------------
// Persistent recurrent kernel, round-13 = round-9 (proven 2960 us) with ONE
// contained change: PARALLEL FINALIZE. Round 4's structural gamble (wave-
// owns-row, 128 blocks) regressed 1.8x: full-s reads per wave quadruple the
// DS-pipe load and the chip-wide max runs over 2048 independent chains.
// Reverted. Structure here: 256 blocks x 1024 threads; block B owns rows
// [16B,+16); wave (h,qd) computes rows 4h..4h+3 over col-quad qd (lane owns
// 16 cols; W patch = 32 VGPRs); merged 7-shuffle butterfly leaves lane l<4
// holding the full qd-partial of row 4h+l IN REGISTER.
// Round-9 tail: waves 1..15 wrote redf, wave 0 serially finalized all 16
// rows (64 redf reads + 16 tanh + pack). NOW: only qd=1,2,3 write redf
// (12 floats per h-group); after barrier B, each qd=0 wave finalizes its
// OWN 4 rows (3 redf reads + own register partial + pv), tanh, packs via
// 1 shuffle, and lanes 0/2 publish its 2 words. Finalize is 4-way parallel
// and publish fires from 4 waves immediately.
// Publish protocol unchanged (proven): 4 slots x 2048 tagged words
// {u32 tag = t+2, 2 x fp16}; word k covers rows 2k,2k+1; thread polls words
// 2tid,2tid+1 of slot t&3 for tag t+1, scatters payload into swizzled
// s2[t&1]. Slot safety (NBUF=4) and s2 double-buffer safety as round 9.
// ---------------------------------------------------------------------------
__global__ __launch_bounds__(1024, 4) void esn_recurrent(
    const float* __restrict__ Whh,            // H*H row-major fp32
    const float* __restrict__ pre_in,         // SEQ*H = X @ W_ih^T  (ws)
    float*       __restrict__ states,         // SEQ*H (inside d_out)
    unsigned long long* __restrict__ part)    // 4*2048 tagged words (d_out scratch)
{
    extern __shared__ char smem[];
    unsigned* s2   = (unsigned*)smem;               // [2][2048] swizzled
    float*    redf = (float*)(smem + 16384);        // [16][4] (cols 0..2 used)

    const int B    = blockIdx.x;       // owns rows [16B, +16)
    const int tid  = threadIdx.x;
    const int wave = tid >> 6;         // 0..15
    const int lane = tid & 63;
    const int h    = wave >> 2;        // row quad: rows 4h..4h+3 (of my 16)
    const int qd   = wave & 3;         // col quad: cols [1024qd, +1024)

    // ---- prologue first: publish s[0] for my rows (gates other blocks) ----
    if (wave == 0) {
        float s0 = 0.f;
        if (lane < 16) {
            s0 = tanh_fast(pre_in[(B << 4) + lane]);
            states[(B << 4) + lane] = s0;
        }
        float a = __shfl(s0, lane << 1);
        float b = __shfl(s0, (lane << 1) + 1);
        if (lane < 8) {
            __half2 p = __floats2half2_rn(a, b);
            unsigned long long wrd = (1ull << 32)
                                   | (unsigned long long)(*(unsigned*)&p);
            __hip_atomic_store(part + (B << 3) + lane, wrd,
                               __ATOMIC_RELAXED, __HIP_MEMORY_SCOPE_AGENT);
        }
    }

    // ---- load my 4x16 W_hh patch into registers (fp16 pairs, once) ----
    uint4 wa0, wb0, wa1, wb1, wa2, wb2, wa3, wb3;
    {
        const float* wsrc = Whh + ((size_t)((B << 4) + (h << 2))) * H
                          + (qd << 10) + (lane << 4);
        const float4* r0 = (const float4*)(wsrc);
        const float4* r1 = (const float4*)(wsrc + H);
        const float4* r2 = (const float4*)(wsrc + 2 * H);
        const float4* r3 = (const float4*)(wsrc + 3 * H);
        wa0 = pack8(r0[0], r0[1]); wb0 = pack8(r0[2], r0[3]);
        wa1 = pack8(r1[0], r1[1]); wb1 = pack8(r1[2], r1[3]);
        wa2 = pack8(r2[0], r2[1]); wb2 = pack8(r2[2], r2[3]);
        wa3 = pack8(r3[0], r3[1]); wb3 = pack8(r3[2], r3[3]);
    }

    for (int t = 0; t < SEQ - 1; ++t) {
        // prefetch pre_in[t+1] for the 4 rows this wave will finalize
        float pv = 0.f;
        if (qd == 0 && lane < 4)
            pv = pre_in[(size_t)(t + 1) * H + (B << 4) + (h << 2) + lane];

        // ---- A. poll s[t] (slot t&3, tag t+1); thread owns words 2tid,2tid+1 ----
        {
            const unsigned long long* pb = part + ((size_t)(t & 3) << 11) + (tid << 1);
            const unsigned want = (unsigned)(t + 1);
            unsigned long long v0, v1;
            for (;;) {
                v0 = __hip_atomic_load(pb,     __ATOMIC_RELAXED, __HIP_MEMORY_SCOPE_AGENT);
                v1 = __hip_atomic_load(pb + 1, __ATOMIC_RELAXED, __HIP_MEMORY_SCOPE_AGENT);
                if ((unsigned)(v0 >> 32) == want && (unsigned)(v1 >> 32) == want) break;
                __builtin_amdgcn_s_sleep(1);
            }
            uint2 w; w.x = (unsigned)v0; w.y = (unsigned)v1;
            *(uint2*)(s2 + ((t & 1) << 11) + swz2(tid << 1)) = w;
        }
        __syncthreads();   // barrier A

        // ---- B. compute rows 4h..4h+3 x cols [1024qd + 16*lane, +16) ----
        const unsigned* sb = s2 + ((t & 1) << 11);
        const int cb = (qd << 9) + (lane << 3);
        uint4 sa = *(const uint4*)(sb + swz2(cb));
        uint4 sc = *(const uint4*)(sb + swz2(cb + 4));

        float a0 = 0.f, a1 = 0.f, a2 = 0.f, a3 = 0.f;
        a0 = fdot2(wa0.x, sa.x, a0); a0 = fdot2(wa0.y, sa.y, a0);
        a0 = fdot2(wa0.z, sa.z, a0); a0 = fdot2(wa0.w, sa.w, a0);
        a0 = fdot2(wb0.x, sc.x, a0); a0 = fdot2(wb0.y, sc.y, a0);
        a0 = fdot2(wb0.z, sc.z, a0); a0 = fdot2(wb0.w, sc.w, a0);
        a1 = fdot2(wa1.x, sa.x, a1); a1 = fdot2(wa1.y, sa.y, a1);
        a1 = fdot2(wa1.z, sa.z, a1); a1 = fdot2(wa1.w, sa.w, a1);
        a1 = fdot2(wb1.x, sc.x, a1); a1 = fdot2(wb1.y, sc.y, a1);
        a1 = fdot2(wb1.z, sc.z, a1); a1 = fdot2(wb1.w, sc.w, a1);
        a2 = fdot2(wa2.x, sa.x, a2); a2 = fdot2(wa2.y, sa.y, a2);
        a2 = fdot2(wa2.z, sa.z, a2); a2 = fdot2(wa2.w, sa.w, a2);
        a2 = fdot2(wb2.x, sc.x, a2); a2 = fdot2(wb2.y, sc.y, a2);
        a2 = fdot2(wb2.z, sc.z, a2); a2 = fdot2(wb2.w, sc.w, a2);
        a3 = fdot2(wa3.x, sa.x, a3); a3 = fdot2(wa3.y, sa.y, a3);
        a3 = fdot2(wa3.z, sa.z, a3); a3 = fdot2(wa3.w, sa.w, a3);
        a3 = fdot2(wb3.x, sc.x, a3); a3 = fdot2(wb3.y, sc.y, a3);
        a3 = fdot2(wb3.z, sc.z, a3); a3 = fdot2(wb3.w, sc.w, a3);

        // ---- merged butterfly: 7 shuffles ----
        float y0 = (lane & 1) ? a0 : a1;
        float x  = (lane & 1) ? a1 : a0;
        x += __shfl_xor(y0, 1);
        float y1 = (lane & 1) ? a2 : a3;
        float z  = (lane & 1) ? a3 : a2;
        z += __shfl_xor(y1, 1);
        float y2 = (lane & 2) ? x : z;
        float u  = (lane & 2) ? z : x;
        u += __shfl_xor(y2, 2);
        u += __shfl_xor(u, 4);
        u += __shfl_xor(u, 8);
        u += __shfl_xor(u, 16);
        u += __shfl_xor(u, 32);
        // lane l (l<4) holds the full col-quad partial for row 4h+l

        if (qd != 0 && lane < 4) redf[(((h << 2) + lane) << 2) + qd - 1] = u;
        __syncthreads();   // barrier B

        // ---- C. parallel finalize: qd=0 wave handles its own 4 rows ----
        if (qd == 0) {
            float sf = 0.f;
            if (lane < 4) {
                const float* rf = redf + (((h << 2) + lane) << 2);
                sf = tanh_fast(u + rf[0] + rf[1] + rf[2] + pv);
                states[(size_t)(t + 1) * H + (B << 4) + (h << 2) + lane] = sf;
            }
            float o = __shfl(sf, (lane & ~1) + 1);  // lane0<-sf(1), lane2<-sf(3)
            if (lane < 4 && (lane & 1) == 0) {
                __half2 p = __floats2half2_rn(sf, o);
                unsigned long long wrd = ((unsigned long long)(unsigned)(t + 2) << 32)
                                       | (unsigned long long)(*(unsigned*)&p);
                __hip_atomic_store(part + ((size_t)((t + 1) & 3) << 11)
                                        + (B << 3) + (h << 1) + (lane >> 1),
                                   wrd, __ATOMIC_RELAXED, __HIP_MEMORY_SCOPE_AGENT);
            }
        }
        // next step's barrier A protects redf reuse; s2 is double-buffered
    }
}

// ---------------------------------------------------------------------------
// Generic fp32 tiled GEMM:  C[MxN] = A[MxK] * B[NxK]^T   (both row-major)
// mode 0: A plain (lda). mode 1: virtual ext row t: [1, X[t], S[t]].
// ---------------------------------------------------------------------------
#define BM 64
#define BN 64
#define BK 32

__global__ __launch_bounds__(256) void gemm_abt(
    const float* __restrict__ A, int lda,
    const float* __restrict__ B, int ldb,
    float*       __restrict__ C, int ldc,
    int Mdim, int N, int K, int mode,
    const float* __restrict__ X, const float* __restrict__ S)
{
    __shared__ __align__(16) float As[BK][BM + 4];
    __shared__ __align__(16) float Bs[BK][BN + 4];

    const int tid = threadIdx.x;
    const int n0  = blockIdx.x * BN;
    const int m0  = blockIdx.y * BM;
    const int tx  = tid & 15;
    const int ty  = tid >> 4;

    float c[4][4] = {};

    for (int k0 = 0; k0 < K; k0 += BK) {
        #pragma unroll
        for (int p = 0; p < 8; ++p) {
            const int idx = tid + p * 256;
            const int mm  = idx >> 5;
            const int kk  = idx & 31;
            const int gk  = k0 + kk;

            float av = 0.f;
            const int gm = m0 + mm;
            if (gm < Mdim && gk < K) {
                if (mode == 0) {
                    av = A[(size_t)gm * lda + gk];
                } else {
                    if (gk == 0)          av = 1.0f;
                    else if (gk <= IDIM)  av = X[(size_t)gm * IDIM + (gk - 1)];
                    else                  av = S[(size_t)gm * H + (gk - 1 - IDIM)];
                }
            }
            As[kk][mm] = av;

            float bv = 0.f;
            const int gn = n0 + mm;
            if (gn < N && gk < K) bv = B[(size_t)gn * ldb + gk];
            Bs[kk][mm] = bv;
        }
        __syncthreads();

        #pragma unroll
        for (int kk = 0; kk < BK; ++kk) {
            float4 a = *(const float4*)&As[kk][ty * 4];
            float4 b = *(const float4*)&Bs[kk][tx * 4];
            float av[4] = {a.x, a.y, a.z, a.w};
            float bv[4] = {b.x, b.y, b.z, b.w};
            #pragma unroll
            for (int i = 0; i < 4; ++i)
                #pragma unroll
                for (int j = 0; j < 4; ++j)
                    c[i][j] += av[i] * bv[j];
        }
        __syncthreads();
    }

    #pragma unroll
    for (int i = 0; i < 4; ++i) {
        const int gm = m0 + ty * 4 + i;
        if (gm >= Mdim) continue;
        #pragma unroll
        for (int j = 0; j < 4; ++j) {
            const int gn = n0 + tx * 4 + j;
            if (gn < N) C[(size_t)gm * ldc + gn] = c[i][j];
        }
    }
}

// ---------------------------------------------------------------------------
// Split-K GEMM for phase 2 (mode-1 virtual A only):
//   Cp[z][M][N] partial over K-slice z. Grid (N/BN, M/BM, 4).
// ---------------------------------------------------------------------------
#define KSLICE 1280   // 40 tiles of 32; slice 3 gets the 1157-tail

__global__ __launch_bounds__(256) void gemm_splitk(
    const float* __restrict__ Bw, int ldb,
    float*       __restrict__ Cp,            // 4 partials, stride M*N
    int Mdim, int N, int K,
    const float* __restrict__ X, const float* __restrict__ S)
{
    __shared__ __align__(16) float As[BK][BM + 4];
    __shared__ __align__(16) float Bs[BK][BN + 4];

    const int tid = threadIdx.x;
    const int n0  = blockIdx.x * BN;
    const int m0  = blockIdx.y * BM;
    const int z   = blockIdx.z;
    const int tx  = tid & 15;
    const int ty  = tid >> 4;

    const int kbeg = z * KSLICE;
    const int kend = min(K, kbeg + KSLICE);

    float c[4][4] = {};

    for (int k0 = kbeg; k0 < kend; k0 += BK) {
        const bool pureS = (k0 >= IDIM + 1) && (k0 + BK <= kend);
        const bool pureX = (k0 > 0) && (k0 + BK <= IDIM + 1);
        #pragma unroll
        for (int p = 0; p < 8; ++p) {
            const int idx = tid + p * 256;
            const int mm  = idx >> 5;
            const int kk  = idx & 31;
            const int gk  = k0 + kk;
            const int gm  = m0 + mm;

            float av = 0.f;
            if (gm < Mdim) {
                if (pureS)      av = S[(size_t)gm * H + (gk - 1 - IDIM)];
                else if (pureX) av = X[(size_t)gm * IDIM + (gk - 1)];
                else if (gk < kend) {
                    if (gk == 0)          av = 1.0f;
                    else if (gk <= IDIM)  av = X[(size_t)gm * IDIM + (gk - 1)];
                    else                  av = S[(size_t)gm * H + (gk - 1 - IDIM)];
                }
            }
            As[kk][mm] = av;

            float bv = 0.f;
            const int gn = n0 + mm;
            if (gn < N && gk < kend) bv = Bw[(size_t)gn * ldb + gk];
            Bs[kk][mm] = bv;
        }
        __syncthreads();

        #pragma unroll
        for (int kk = 0; kk < BK; ++kk) {
            float4 a = *(const float4*)&As[kk][ty * 4];
            float4 b = *(const float4*)&Bs[kk][tx * 4];
            float av[4] = {a.x, a.y, a.z, a.w};
            float bv[4] = {b.x, b.y, b.z, b.w};
            #pragma unroll
            for (int i = 0; i < 4; ++i)
                #pragma unroll
                for (int j = 0; j < 4; ++j)
                    c[i][j] += av[i] * bv[j];
        }
        __syncthreads();
    }

    float* Cz = Cp + (size_t)z * ((size_t)SEQ * IDIM);
    #pragma unroll
    for (int i = 0; i < 4; ++i) {
        const int gm = m0 + ty * 4 + i;
        if (gm >= Mdim) continue;
        #pragma unroll
        for (int j = 0; j < 4; ++j) {
            const int gn = n0 + tx * 4 + j;
            if (gn < N) Cz[(size_t)gm * N + gn] = c[i][j];
        }
    }
}

// out[i] = sum of 4 split-K partials (SEQ*IDIM floats, /4 exact)
__global__ __launch_bounds__(256) void reduce4(
    const float4* __restrict__ p, float4* __restrict__ o, int n4)
{
    const size_t stride = (size_t)SEQ * IDIM / 4;
    for (int i = blockIdx.x * 256 + threadIdx.x; i < n4; i += gridDim.x * 256) {
        float4 a = p[i];
        float4 b = p[i + stride];
        float4 c = p[i + 2 * stride];
        float4 d = p[i + 3 * stride];
        float4 r;
        r.x = a.x + b.x + c.x + d.x;
        r.y = a.y + b.y + c.y + d.y;
        r.z = a.z + b.z + c.z + d.z;
        r.w = a.w + b.w + c.w + d.w;
        o[i] = r;
    }
}

// ---------------------------------------------------------------------------
// Launcher
// ---------------------------------------------------------------------------
extern "C" void kernel_launch(void* const* d_in, const int* in_sizes, int n_in,
                              void* d_out, int out_size, void* d_ws, size_t ws_size,
                              hipStream_t stream) {
    const float* inputs = (const float*)d_in[0];
    // d_in[1] = initial state (zeros) — folded out
    const float* W_ih   = (const float*)d_in[2];
    const float* W_hh   = (const float*)d_in[3];
    const float* W_out  = (const float*)d_in[4];

    float* out    = (float*)d_out;                 // SEQ*IDIM
    float* states = out + (size_t)SEQ * IDIM;      // SEQ*H

    float* pre_in = (float*)d_ws;                  // SEQ*H fp32 (16.4 MB)
    float* cpart  = pre_in + (size_t)SEQ * H;      // 4 * SEQ*IDIM fp32 (14.4 MB)

    const size_t ws_needed = ((size_t)SEQ * H + 4ull * SEQ * IDIM) * sizeof(float);
    const bool   use_splitk = (ws_size >= ws_needed);

    // Tagged s-broadcast scratch in the outputs region of d_out (overwritten
    // by phase 2): 4 slots * 2048 words * 8 B = 64 KB. Harness 0xAA poison
    // gives tag 0xAAAAAAAA, never equal to a live tag (1..1000).
    unsigned long long* part = (unsigned long long*)out;

    (void)hipFuncSetAttribute((const void*)esn_recurrent,
                              hipFuncAttributeMaxDynamicSharedMemorySize,
                              LDS_BYTES);

    // Phase 0: pre_in[t][r] = sum_i X[t][i] * W_ih[r][i]
    gemm_abt<<<dim3(H / BN, (SEQ + BM - 1) / BM), 256, 0, stream>>>(
        inputs, IDIM, W_ih, IDIM, pre_in, H, SEQ, H, IDIM, 0, nullptr, nullptr);

    // Phase 1: persistent sequential recurrence (256 blocks x 1024 threads)
    {
        const float* whh_p = W_hh;
        const float* pin_p = pre_in;
        float* st_p = states;
        unsigned long long* part_p = part;
        void* args[] = { (void*)&whh_p, (void*)&pin_p, (void*)&st_p, (void*)&part_p };
        hipLaunchCooperativeKernel((const void*)esn_recurrent,
                                   dim3(256), dim3(1024), args, LDS_BYTES, stream);
    }

    // Phase 2: outputs[t][i] = sum_k ext[t][k] * W_out[i][k]
    if (use_splitk) {
        gemm_splitk<<<dim3((IDIM + BN - 1) / BN, (SEQ + BM - 1) / BM, 4),
                      256, 0, stream>>>(
            W_out, 1 + IDIM + H, cpart, SEQ, IDIM, 1 + IDIM + H, inputs, states);
        const int n4 = SEQ * IDIM / 4;
        reduce4<<<dim3(880), 256, 0, stream>>>(
            (const float4*)cpart, (float4*)out, n4);
    } else {
        gemm_abt<<<dim3((IDIM + BN - 1) / BN, (SEQ + BM - 1) / BM), 256, 0, stream>>>(
            nullptr, 0, W_out, 1 + IDIM + H, out, IDIM,
            SEQ, IDIM, 1 + IDIM + H, 1, inputs, states);
    }
}

// Round 6
// 4003.196 us; speedup vs baseline: 1.5579x; 1.5013x over previous
//
#include <hip/hip_runtime.h>
#include <hip/hip_fp16.h>

#define SEQ  1000
#define IDIM 900
#define H    4096

// LDS carve-up for esn_recurrent (W_hh lives in REGISTERS):
//   s2   : uint[2][2048]  s[t] fp16 pairs, double-buffered = 16384 B
//   redf : float[16][5]   per-(row,colquad) partials       =   320 B
#define LDS_BYTES (16384 + 320)

typedef _Float16 h2_t __attribute__((ext_vector_type(2)));

__device__ __forceinline__ float fdot2(unsigned a, unsigned b, float c) {
#if __has_builtin(__builtin_amdgcn_fdot2)
    return __builtin_amdgcn_fdot2(__builtin_bit_cast(h2_t, a),
                                  __builtin_bit_cast(h2_t, b), c, false);
#else
    h2_t ha = __builtin_bit_cast(h2_t, a);
    h2_t hb = __builtin_bit_cast(h2_t, b);
    return c + (float)ha.x * (float)hb.x + (float)ha.y * (float)hb.y;
#endif
}

__device__ __forceinline__ float tanh_fast(float x) {
    float ax = __builtin_fabsf(x);
    float e  = __expf(-2.0f * ax);
    float t  = (1.0f - e) / (1.0f + e);
    return __builtin_copysignf(t, x);
}

// Bank swizzle on s2 dword indices: XOR bits [4:2] with bits [7:5].
__device__ __forceinline__ int swz2(int d) { return d ^ (((d >> 5) & 7) << 2); }

__device__ __forceinline__ uint4 pack8(float4 f0, float4 f1) {
    __half2 p; uint4 u;
    p = __floats2half2_rn(f0.x, f0.y); u.x = *(unsigned*)&p;
    p = __floats2half2_rn(f0.z, f0.w); u.y = *(unsigned*)&p;
    p = __floats2half2_rn(f1.x, f1.y); u.z = *(unsigned*)&p;
    p = __floats2half2_rn(f1.z, f1.w); u.w = *(unsigned*)&p;
    return u;
}

// ---------------------------------------------------------------------------
// Persistent recurrent kernel: BYTE-EXACT round-9 revert (proven 2960 us).
// Rounds 11 (wave-owns-row) and 13 (parallel finalize) both regressed:
// the qd=0 publisher waves {0,4,8,12} serialize on one SIMD and sparse
// 2-lane publishes split the coalesced 64 B store into partial-line
// transactions (WRITE_SIZE 32->48 MB). The wave-0 SIMT finalize + single
// coalesced publish is the proven tail. Step period ~2.96 us is approx
// the chip-wide broadcast round-trip floor; no further tail surgery.
// ---------------------------------------------------------------------------
__global__ __launch_bounds__(1024, 4) void esn_recurrent(
    const float* __restrict__ Whh,            // H*H row-major fp32
    const float* __restrict__ pre_in,         // SEQ*H = X @ W_ih^T  (ws)
    float*       __restrict__ states,         // SEQ*H (inside d_out)
    unsigned long long* __restrict__ part)    // 4*2048 tagged words (d_out scratch)
{
    extern __shared__ char smem[];
    unsigned* s2   = (unsigned*)smem;               // [2][2048] swizzled
    float*    redf = (float*)(smem + 16384);        // [16][5]

    const int B    = blockIdx.x;       // owns rows [16B, +16)
    const int tid  = threadIdx.x;
    const int wave = tid >> 6;         // 0..15
    const int lane = tid & 63;
    const int h    = wave >> 2;        // row quad: rows 4h..4h+3 (of my 16)
    const int qd   = wave & 3;         // col quad: cols [1024qd, +1024)

    // ---- prologue first: publish s[0] for my rows (gates other blocks) ----
    if (wave == 0) {
        float s0 = 0.f;
        if (lane < 16) {
            s0 = tanh_fast(pre_in[(B << 4) + lane]);
            states[(B << 4) + lane] = s0;
        }
        float a = __shfl(s0, lane << 1);
        float b = __shfl(s0, (lane << 1) + 1);
        if (lane < 8) {
            __half2 p = __floats2half2_rn(a, b);
            unsigned long long wrd = (1ull << 32)
                                   | (unsigned long long)(*(unsigned*)&p);
            __hip_atomic_store(part + (B << 3) + lane, wrd,
                               __ATOMIC_RELAXED, __HIP_MEMORY_SCOPE_AGENT);
        }
    }

    // ---- load my 4x16 W_hh patch into registers (fp16 pairs, once) ----
    uint4 wa0, wb0, wa1, wb1, wa2, wb2, wa3, wb3;
    {
        const float* wsrc = Whh + ((size_t)((B << 4) + (h << 2))) * H
                          + (qd << 10) + (lane << 4);
        const float4* r0 = (const float4*)(wsrc);
        const float4* r1 = (const float4*)(wsrc + H);
        const float4* r2 = (const float4*)(wsrc + 2 * H);
        const float4* r3 = (const float4*)(wsrc + 3 * H);
        wa0 = pack8(r0[0], r0[1]); wb0 = pack8(r0[2], r0[3]);
        wa1 = pack8(r1[0], r1[1]); wb1 = pack8(r1[2], r1[3]);
        wa2 = pack8(r2[0], r2[1]); wb2 = pack8(r2[2], r2[3]);
        wa3 = pack8(r3[0], r3[1]); wb3 = pack8(r3[2], r3[3]);
    }

    for (int t = 0; t < SEQ - 1; ++t) {
        float pv = 0.f;
        if (tid < 16) pv = pre_in[(size_t)(t + 1) * H + (B << 4) + tid];

        // ---- A. poll s[t] (slot t&3, tag t+1); thread owns words 2tid,2tid+1 ----
        {
            const unsigned long long* pb = part + ((size_t)(t & 3) << 11) + (tid << 1);
            const unsigned want = (unsigned)(t + 1);
            unsigned long long v0, v1;
            for (;;) {
                v0 = __hip_atomic_load(pb,     __ATOMIC_RELAXED, __HIP_MEMORY_SCOPE_AGENT);
                v1 = __hip_atomic_load(pb + 1, __ATOMIC_RELAXED, __HIP_MEMORY_SCOPE_AGENT);
                if ((unsigned)(v0 >> 32) == want && (unsigned)(v1 >> 32) == want) break;
                __builtin_amdgcn_s_sleep(1);
            }
            uint2 w; w.x = (unsigned)v0; w.y = (unsigned)v1;
            *(uint2*)(s2 + ((t & 1) << 11) + swz2(tid << 1)) = w;
        }
        __syncthreads();   // barrier A

        // ---- B. compute rows 4h..4h+3 x cols [1024qd + 16*lane, +16) ----
        const unsigned* sb = s2 + ((t & 1) << 11);
        const int cb = (qd << 9) + (lane << 3);
        uint4 sa = *(const uint4*)(sb + swz2(cb));
        uint4 sc = *(const uint4*)(sb + swz2(cb + 4));

        float a0 = 0.f, a1 = 0.f, a2 = 0.f, a3 = 0.f;
        a0 = fdot2(wa0.x, sa.x, a0); a0 = fdot2(wa0.y, sa.y, a0);
        a0 = fdot2(wa0.z, sa.z, a0); a0 = fdot2(wa0.w, sa.w, a0);
        a0 = fdot2(wb0.x, sc.x, a0); a0 = fdot2(wb0.y, sc.y, a0);
        a0 = fdot2(wb0.z, sc.z, a0); a0 = fdot2(wb0.w, sc.w, a0);
        a1 = fdot2(wa1.x, sa.x, a1); a1 = fdot2(wa1.y, sa.y, a1);
        a1 = fdot2(wa1.z, sa.z, a1); a1 = fdot2(wa1.w, sa.w, a1);
        a1 = fdot2(wb1.x, sc.x, a1); a1 = fdot2(wb1.y, sc.y, a1);
        a1 = fdot2(wb1.z, sc.z, a1); a1 = fdot2(wb1.w, sc.w, a1);
        a2 = fdot2(wa2.x, sa.x, a2); a2 = fdot2(wa2.y, sa.y, a2);
        a2 = fdot2(wa2.z, sa.z, a2); a2 = fdot2(wa2.w, sa.w, a2);
        a2 = fdot2(wb2.x, sc.x, a2); a2 = fdot2(wb2.y, sc.y, a2);
        a2 = fdot2(wb2.z, sc.z, a2); a2 = fdot2(wb2.w, sc.w, a2);
        a3 = fdot2(wa3.x, sa.x, a3); a3 = fdot2(wa3.y, sa.y, a3);
        a3 = fdot2(wa3.z, sa.z, a3); a3 = fdot2(wa3.w, sa.w, a3);
        a3 = fdot2(wb3.x, sc.x, a3); a3 = fdot2(wb3.y, sc.y, a3);
        a3 = fdot2(wb3.z, sc.z, a3); a3 = fdot2(wb3.w, sc.w, a3);

        // ---- merged butterfly: 7 shuffles ----
        float y0 = (lane & 1) ? a0 : a1;
        float x  = (lane & 1) ? a1 : a0;
        x += __shfl_xor(y0, 1);
        float y1 = (lane & 1) ? a2 : a3;
        float z  = (lane & 1) ? a3 : a2;
        z += __shfl_xor(y1, 1);
        float y2 = (lane & 2) ? x : z;
        float u  = (lane & 2) ? z : x;
        u += __shfl_xor(y2, 2);
        u += __shfl_xor(u, 4);
        u += __shfl_xor(u, 8);
        u += __shfl_xor(u, 16);
        u += __shfl_xor(u, 32);

        if (lane < 4) redf[((h << 2) + lane) * 5 + qd] = u;
        __syncthreads();   // barrier B

        // ---- C. finalize (wave 0 only) ----
        if (wave == 0) {
            float sf = 0.f;
            if (lane < 16) {
                const float* rf = redf + lane * 5;
                sf = tanh_fast(rf[0] + rf[1] + rf[2] + rf[3] + pv);
                states[(size_t)(t + 1) * H + (B << 4) + lane] = sf;
            }
            float a = __shfl(sf, lane << 1);
            float b = __shfl(sf, (lane << 1) + 1);
            if (lane < 8) {
                __half2 p = __floats2half2_rn(a, b);
                unsigned long long wrd = ((unsigned long long)(unsigned)(t + 2) << 32)
                                       | (unsigned long long)(*(unsigned*)&p);
                __hip_atomic_store(part + ((size_t)((t + 1) & 3) << 11) + (B << 3) + lane,
                                   wrd, __ATOMIC_RELAXED, __HIP_MEMORY_SCOPE_AGENT);
            }
        }
    }
}

// ---------------------------------------------------------------------------
// fp32 tiled GEMM, round-14: 128x128 tile, BK=16, 8x8 per-thread microtile.
// C[MxN] = A[MxK] * B[NxK]^T. mode 0: plain A. mode 1: virtual ext row
// [1, X[t], S[t]]. Same guard/branch logic as the proven 64x64 kernel;
// only tile geometry changed (64 FMA per 4 LDS b128 reads vs 16 per 2).
// A-fragment reads are uniform per 16-lane group (broadcast); B-fragment
// reads stride 32 B (conflict-free).
// ---------------------------------------------------------------------------
#define GBM 128
#define GBN 128
#define GBK 16

__global__ __launch_bounds__(256) void gemm_abt(
    const float* __restrict__ A, int lda,
    const float* __restrict__ B, int ldb,
    float*       __restrict__ C, int ldc,
    int Mdim, int N, int K, int mode,
    const float* __restrict__ X, const float* __restrict__ S)
{
    __shared__ __align__(16) float As[GBK][GBM + 4];
    __shared__ __align__(16) float Bs[GBK][GBN + 4];

    const int tid = threadIdx.x;
    const int n0  = blockIdx.x * GBN;
    const int m0  = blockIdx.y * GBM;
    const int tx  = tid & 15;     // col group of 8
    const int ty  = tid >> 4;     // row group of 8

    float c[8][8] = {};

    for (int k0 = 0; k0 < K; k0 += GBK) {
        #pragma unroll
        for (int p = 0; p < 8; ++p) {
            const int idx = tid + p * 256;
            const int mm  = idx >> 4;      // 0..127
            const int kk  = idx & 15;
            const int gk  = k0 + kk;

            float av = 0.f;
            const int gm = m0 + mm;
            if (gm < Mdim && gk < K) {
                if (mode == 0) {
                    av = A[(size_t)gm * lda + gk];
                } else {
                    if (gk == 0)          av = 1.0f;
                    else if (gk <= IDIM)  av = X[(size_t)gm * IDIM + (gk - 1)];
                    else                  av = S[(size_t)gm * H + (gk - 1 - IDIM)];
                }
            }
            As[kk][mm] = av;

            float bv = 0.f;
            const int gn = n0 + mm;
            if (gn < N && gk < K) bv = B[(size_t)gn * ldb + gk];
            Bs[kk][mm] = bv;
        }
        __syncthreads();

        #pragma unroll
        for (int kk = 0; kk < GBK; ++kk) {
            float4 x0 = *(const float4*)&As[kk][ty * 8];
            float4 x1 = *(const float4*)&As[kk][ty * 8 + 4];
            float4 y0 = *(const float4*)&Bs[kk][tx * 8];
            float4 y1 = *(const float4*)&Bs[kk][tx * 8 + 4];
            float av[8] = {x0.x, x0.y, x0.z, x0.w, x1.x, x1.y, x1.z, x1.w};
            float bv[8] = {y0.x, y0.y, y0.z, y0.w, y1.x, y1.y, y1.z, y1.w};
            #pragma unroll
            for (int i = 0; i < 8; ++i)
                #pragma unroll
                for (int j = 0; j < 8; ++j)
                    c[i][j] += av[i] * bv[j];
        }
        __syncthreads();
    }

    #pragma unroll
    for (int i = 0; i < 8; ++i) {
        const int gm = m0 + ty * 8 + i;
        if (gm >= Mdim) continue;
        #pragma unroll
        for (int j = 0; j < 8; ++j) {
            const int gn = n0 + tx * 8 + j;
            if (gn < N) C[(size_t)gm * ldc + gn] = c[i][j];
        }
    }
}

// ---------------------------------------------------------------------------
// Split-K GEMM for phase 2 (mode-1 virtual A), same 128x128x16 geometry.
//   Cp[z][M][N] partial over K-slice z. Grid (N/GBN, M/GBM, 4).
// ---------------------------------------------------------------------------
#define KSLICE 1280   // 80 tiles of 16; slice 3 gets the 1157-tail

__global__ __launch_bounds__(256) void gemm_splitk(
    const float* __restrict__ Bw, int ldb,
    float*       __restrict__ Cp,            // 4 partials, stride M*N
    int Mdim, int N, int K,
    const float* __restrict__ X, const float* __restrict__ S)
{
    __shared__ __align__(16) float As[GBK][GBM + 4];
    __shared__ __align__(16) float Bs[GBK][GBN + 4];

    const int tid = threadIdx.x;
    const int n0  = blockIdx.x * GBN;
    const int m0  = blockIdx.y * GBM;
    const int z   = blockIdx.z;
    const int tx  = tid & 15;
    const int ty  = tid >> 4;

    const int kbeg = z * KSLICE;
    const int kend = min(K, kbeg + KSLICE);

    float c[8][8] = {};

    for (int k0 = kbeg; k0 < kend; k0 += GBK) {
        const bool pureS = (k0 >= IDIM + 1) && (k0 + GBK <= kend);
        const bool pureX = (k0 > 0) && (k0 + GBK <= IDIM + 1);
        #pragma unroll
        for (int p = 0; p < 8; ++p) {
            const int idx = tid + p * 256;
            const int mm  = idx >> 4;
            const int kk  = idx & 15;
            const int gk  = k0 + kk;
            const int gm  = m0 + mm;

            float av = 0.f;
            if (gm < Mdim) {
                if (pureS)      av = S[(size_t)gm * H + (gk - 1 - IDIM)];
                else if (pureX) av = X[(size_t)gm * IDIM + (gk - 1)];
                else if (gk < kend) {
                    if (gk == 0)          av = 1.0f;
                    else if (gk <= IDIM)  av = X[(size_t)gm * IDIM + (gk - 1)];
                    else                  av = S[(size_t)gm * H + (gk - 1 - IDIM)];
                }
            }
            As[kk][mm] = av;

            float bv = 0.f;
            const int gn = n0 + mm;
            if (gn < N && gk < kend) bv = Bw[(size_t)gn * ldb + gk];
            Bs[kk][mm] = bv;
        }
        __syncthreads();

        #pragma unroll
        for (int kk = 0; kk < GBK; ++kk) {
            float4 x0 = *(const float4*)&As[kk][ty * 8];
            float4 x1 = *(const float4*)&As[kk][ty * 8 + 4];
            float4 y0 = *(const float4*)&Bs[kk][tx * 8];
            float4 y1 = *(const float4*)&Bs[kk][tx * 8 + 4];
            float av[8] = {x0.x, x0.y, x0.z, x0.w, x1.x, x1.y, x1.z, x1.w};
            float bv[8] = {y0.x, y0.y, y0.z, y0.w, y1.x, y1.y, y1.z, y1.w};
            #pragma unroll
            for (int i = 0; i < 8; ++i)
                #pragma unroll
                for (int j = 0; j < 8; ++j)
                    c[i][j] += av[i] * bv[j];
        }
        __syncthreads();
    }

    float* Cz = Cp + (size_t)z * ((size_t)SEQ * IDIM);
    #pragma unroll
    for (int i = 0; i < 8; ++i) {
        const int gm = m0 + ty * 8 + i;
        if (gm >= Mdim) continue;
        #pragma unroll
        for (int j = 0; j < 8; ++j) {
            const int gn = n0 + tx * 8 + j;
            if (gn < N) Cz[(size_t)gm * N + gn] = c[i][j];
        }
    }
}

// out[i] = sum of 4 split-K partials (SEQ*IDIM floats, /4 exact)
__global__ __launch_bounds__(256) void reduce4(
    const float4* __restrict__ p, float4* __restrict__ o, int n4)
{
    const size_t stride = (size_t)SEQ * IDIM / 4;
    for (int i = blockIdx.x * 256 + threadIdx.x; i < n4; i += gridDim.x * 256) {
        float4 a = p[i];
        float4 b = p[i + stride];
        float4 c = p[i + 2 * stride];
        float4 d = p[i + 3 * stride];
        float4 r;
        r.x = a.x + b.x + c.x + d.x;
        r.y = a.y + b.y + c.y + d.y;
        r.z = a.z + b.z + c.z + d.z;
        r.w = a.w + b.w + c.w + d.w;
        o[i] = r;
    }
}

// ---------------------------------------------------------------------------
// Launcher
// ---------------------------------------------------------------------------
extern "C" void kernel_launch(void* const* d_in, const int* in_sizes, int n_in,
                              void* d_out, int out_size, void* d_ws, size_t ws_size,
                              hipStream_t stream) {
    const float* inputs = (const float*)d_in[0];
    // d_in[1] = initial state (zeros) — folded out
    const float* W_ih   = (const float*)d_in[2];
    const float* W_hh   = (const float*)d_in[3];
    const float* W_out  = (const float*)d_in[4];

    float* out    = (float*)d_out;                 // SEQ*IDIM
    float* states = out + (size_t)SEQ * IDIM;      // SEQ*H

    float* pre_in = (float*)d_ws;                  // SEQ*H fp32 (16.4 MB)
    float* cpart  = pre_in + (size_t)SEQ * H;      // 4 * SEQ*IDIM fp32 (14.4 MB)

    const size_t ws_needed = ((size_t)SEQ * H + 4ull * SEQ * IDIM) * sizeof(float);
    const bool   use_splitk = (ws_size >= ws_needed);

    // Tagged s-broadcast scratch in the outputs region of d_out (overwritten
    // by phase 2): 4 slots * 2048 words * 8 B = 64 KB. Harness 0xAA poison
    // gives tag 0xAAAAAAAA, never equal to a live tag (1..1000).
    unsigned long long* part = (unsigned long long*)out;

    (void)hipFuncSetAttribute((const void*)esn_recurrent,
                              hipFuncAttributeMaxDynamicSharedMemorySize,
                              LDS_BYTES);

    // Phase 0: pre_in[t][r] = sum_i X[t][i] * W_ih[r][i]
    gemm_abt<<<dim3(H / GBN, (SEQ + GBM - 1) / GBM), 256, 0, stream>>>(
        inputs, IDIM, W_ih, IDIM, pre_in, H, SEQ, H, IDIM, 0, nullptr, nullptr);

    // Phase 1: persistent sequential recurrence (256 blocks x 1024 threads)
    {
        const float* whh_p = W_hh;
        const float* pin_p = pre_in;
        float* st_p = states;
        unsigned long long* part_p = part;
        void* args[] = { (void*)&whh_p, (void*)&pin_p, (void*)&st_p, (void*)&part_p };
        hipLaunchCooperativeKernel((const void*)esn_recurrent,
                                   dim3(256), dim3(1024), args, LDS_BYTES, stream);
    }

    // Phase 2: outputs[t][i] = sum_k ext[t][k] * W_out[i][k]
    if (use_splitk) {
        gemm_splitk<<<dim3((IDIM + GBN - 1) / GBN, (SEQ + GBM - 1) / GBM, 4),
                      256, 0, stream>>>(
            W_out, 1 + IDIM + H, cpart, SEQ, IDIM, 1 + IDIM + H, inputs, states);
        const int n4 = SEQ * IDIM / 4;
        reduce4<<<dim3(880), 256, 0, stream>>>(
            (const float4*)cpart, (float4*)out, n4);
    } else {
        gemm_abt<<<dim3((IDIM + GBN - 1) / GBN, (SEQ + GBM - 1) / GBM), 256, 0, stream>>>(
            nullptr, 0, W_out, 1 + IDIM + H, out, IDIM,
            SEQ, IDIM, 1 + IDIM + H, 1, inputs, states);
    }
}

// Round 7
// 3535.721 us; speedup vs baseline: 1.7638x; 1.1322x over previous
//
#include <hip/hip_runtime.h>
#include <hip/hip_fp16.h>

#define SEQ  1000
#define IDIM 900
#define H    4096

// LDS carve-up for esn_recurrent (W_hh lives in REGISTERS):
//   s2   : uint[2][2048]  s[t] fp16 pairs, double-buffered = 16384 B
//   redf : float[16][5]   per-(row,colquad) partials       =   320 B
#define LDS_BYTES (16384 + 320)

typedef _Float16 h2_t __attribute__((ext_vector_type(2)));

__device__ __forceinline__ float fdot2(unsigned a, unsigned b, float c) {
#if __has_builtin(__builtin_amdgcn_fdot2)
    return __builtin_amdgcn_fdot2(__builtin_bit_cast(h2_t, a),
                                  __builtin_bit_cast(h2_t, b), c, false);
#else
    h2_t ha = __builtin_bit_cast(h2_t, a);
    h2_t hb = __builtin_bit_cast(h2_t, b);
    return c + (float)ha.x * (float)hb.x + (float)ha.y * (float)hb.y;
#endif
}

__device__ __forceinline__ float tanh_fast(float x) {
    float ax = __builtin_fabsf(x);
    float e  = __expf(-2.0f * ax);
    float t  = (1.0f - e) / (1.0f + e);
    return __builtin_copysignf(t, x);
}

// Bank swizzle on s2 dword indices: XOR bits [4:2] with bits [7:5].
__device__ __forceinline__ int swz2(int d) { return d ^ (((d >> 5) & 7) << 2); }

__device__ __forceinline__ uint4 pack8(float4 f0, float4 f1) {
    __half2 p; uint4 u;
    p = __floats2half2_rn(f0.x, f0.y); u.x = *(unsigned*)&p;
    p = __floats2half2_rn(f0.z, f0.w); u.y = *(unsigned*)&p;
    p = __floats2half2_rn(f1.x, f1.y); u.z = *(unsigned*)&p;
    p = __floats2half2_rn(f1.z, f1.w); u.w = *(unsigned*)&p;
    return u;
}

// ---------------------------------------------------------------------------
// Persistent recurrent kernel: BYTE-EXACT round-9 structure (proven 2960-2985
// us, reproduced twice). Step period ~2.97 us ~= chip-wide broadcast round-
// trip floor. DO NOT TOUCH: rounds 11/13 tail restructures both regressed.
// ---------------------------------------------------------------------------
__global__ __launch_bounds__(1024, 4) void esn_recurrent(
    const float* __restrict__ Whh,            // H*H row-major fp32
    const float* __restrict__ pre_in,         // SEQ*H = X @ W_ih^T  (ws)
    float*       __restrict__ states,         // SEQ*H (inside d_out)
    unsigned long long* __restrict__ part)    // 4*2048 tagged words (d_out scratch)
{
    extern __shared__ char smem[];
    unsigned* s2   = (unsigned*)smem;               // [2][2048] swizzled
    float*    redf = (float*)(smem + 16384);        // [16][5]

    const int B    = blockIdx.x;       // owns rows [16B, +16)
    const int tid  = threadIdx.x;
    const int wave = tid >> 6;         // 0..15
    const int lane = tid & 63;
    const int h    = wave >> 2;        // row quad: rows 4h..4h+3 (of my 16)
    const int qd   = wave & 3;         // col quad: cols [1024qd, +1024)

    // ---- prologue first: publish s[0] for my rows (gates other blocks) ----
    if (wave == 0) {
        float s0 = 0.f;
        if (lane < 16) {
            s0 = tanh_fast(pre_in[(B << 4) + lane]);
            states[(B << 4) + lane] = s0;
        }
        float a = __shfl(s0, lane << 1);
        float b = __shfl(s0, (lane << 1) + 1);
        if (lane < 8) {
            __half2 p = __floats2half2_rn(a, b);
            unsigned long long wrd = (1ull << 32)
                                   | (unsigned long long)(*(unsigned*)&p);
            __hip_atomic_store(part + (B << 3) + lane, wrd,
                               __ATOMIC_RELAXED, __HIP_MEMORY_SCOPE_AGENT);
        }
    }

    // ---- load my 4x16 W_hh patch into registers (fp16 pairs, once) ----
    uint4 wa0, wb0, wa1, wb1, wa2, wb2, wa3, wb3;
    {
        const float* wsrc = Whh + ((size_t)((B << 4) + (h << 2))) * H
                          + (qd << 10) + (lane << 4);
        const float4* r0 = (const float4*)(wsrc);
        const float4* r1 = (const float4*)(wsrc + H);
        const float4* r2 = (const float4*)(wsrc + 2 * H);
        const float4* r3 = (const float4*)(wsrc + 3 * H);
        wa0 = pack8(r0[0], r0[1]); wb0 = pack8(r0[2], r0[3]);
        wa1 = pack8(r1[0], r1[1]); wb1 = pack8(r1[2], r1[3]);
        wa2 = pack8(r2[0], r2[1]); wb2 = pack8(r2[2], r2[3]);
        wa3 = pack8(r3[0], r3[1]); wb3 = pack8(r3[2], r3[3]);
    }

    for (int t = 0; t < SEQ - 1; ++t) {
        float pv = 0.f;
        if (tid < 16) pv = pre_in[(size_t)(t + 1) * H + (B << 4) + tid];

        // ---- A. poll s[t] (slot t&3, tag t+1); thread owns words 2tid,2tid+1 ----
        {
            const unsigned long long* pb = part + ((size_t)(t & 3) << 11) + (tid << 1);
            const unsigned want = (unsigned)(t + 1);
            unsigned long long v0, v1;
            for (;;) {
                v0 = __hip_atomic_load(pb,     __ATOMIC_RELAXED, __HIP_MEMORY_SCOPE_AGENT);
                v1 = __hip_atomic_load(pb + 1, __ATOMIC_RELAXED, __HIP_MEMORY_SCOPE_AGENT);
                if ((unsigned)(v0 >> 32) == want && (unsigned)(v1 >> 32) == want) break;
                __builtin_amdgcn_s_sleep(1);
            }
            uint2 w; w.x = (unsigned)v0; w.y = (unsigned)v1;
            *(uint2*)(s2 + ((t & 1) << 11) + swz2(tid << 1)) = w;
        }
        __syncthreads();   // barrier A

        // ---- B. compute rows 4h..4h+3 x cols [1024qd + 16*lane, +16) ----
        const unsigned* sb = s2 + ((t & 1) << 11);
        const int cb = (qd << 9) + (lane << 3);
        uint4 sa = *(const uint4*)(sb + swz2(cb));
        uint4 sc = *(const uint4*)(sb + swz2(cb + 4));

        float a0 = 0.f, a1 = 0.f, a2 = 0.f, a3 = 0.f;
        a0 = fdot2(wa0.x, sa.x, a0); a0 = fdot2(wa0.y, sa.y, a0);
        a0 = fdot2(wa0.z, sa.z, a0); a0 = fdot2(wa0.w, sa.w, a0);
        a0 = fdot2(wb0.x, sc.x, a0); a0 = fdot2(wb0.y, sc.y, a0);
        a0 = fdot2(wb0.z, sc.z, a0); a0 = fdot2(wb0.w, sc.w, a0);
        a1 = fdot2(wa1.x, sa.x, a1); a1 = fdot2(wa1.y, sa.y, a1);
        a1 = fdot2(wa1.z, sa.z, a1); a1 = fdot2(wa1.w, sa.w, a1);
        a1 = fdot2(wb1.x, sc.x, a1); a1 = fdot2(wb1.y, sc.y, a1);
        a1 = fdot2(wb1.z, sc.z, a1); a1 = fdot2(wb1.w, sc.w, a1);
        a2 = fdot2(wa2.x, sa.x, a2); a2 = fdot2(wa2.y, sa.y, a2);
        a2 = fdot2(wa2.z, sa.z, a2); a2 = fdot2(wa2.w, sa.w, a2);
        a2 = fdot2(wb2.x, sc.x, a2); a2 = fdot2(wb2.y, sc.y, a2);
        a2 = fdot2(wb2.z, sc.z, a2); a2 = fdot2(wb2.w, sc.w, a2);
        a3 = fdot2(wa3.x, sa.x, a3); a3 = fdot2(wa3.y, sa.y, a3);
        a3 = fdot2(wa3.z, sa.z, a3); a3 = fdot2(wa3.w, sa.w, a3);
        a3 = fdot2(wb3.x, sc.x, a3); a3 = fdot2(wb3.y, sc.y, a3);
        a3 = fdot2(wb3.z, sc.z, a3); a3 = fdot2(wb3.w, sc.w, a3);

        // ---- merged butterfly: 7 shuffles ----
        float y0 = (lane & 1) ? a0 : a1;
        float x  = (lane & 1) ? a1 : a0;
        x += __shfl_xor(y0, 1);
        float y1 = (lane & 1) ? a2 : a3;
        float z  = (lane & 1) ? a3 : a2;
        z += __shfl_xor(y1, 1);
        float y2 = (lane & 2) ? x : z;
        float u  = (lane & 2) ? z : x;
        u += __shfl_xor(y2, 2);
        u += __shfl_xor(u, 4);
        u += __shfl_xor(u, 8);
        u += __shfl_xor(u, 16);
        u += __shfl_xor(u, 32);

        if (lane < 4) redf[((h << 2) + lane) * 5 + qd] = u;
        __syncthreads();   // barrier B

        // ---- C. finalize (wave 0 only) ----
        if (wave == 0) {
            float sf = 0.f;
            if (lane < 16) {
                const float* rf = redf + lane * 5;
                sf = tanh_fast(rf[0] + rf[1] + rf[2] + rf[3] + pv);
                states[(size_t)(t + 1) * H + (B << 4) + lane] = sf;
            }
            float a = __shfl(sf, lane << 1);
            float b = __shfl(sf, (lane << 1) + 1);
            if (lane < 8) {
                __half2 p = __floats2half2_rn(a, b);
                unsigned long long wrd = ((unsigned long long)(unsigned)(t + 2) << 32)
                                       | (unsigned long long)(*(unsigned*)&p);
                __hip_atomic_store(part + ((size_t)((t + 1) & 3) << 11) + (B << 3) + lane,
                                   wrd, __ATOMIC_RELAXED, __HIP_MEMORY_SCOPE_AGENT);
            }
        }
    }
}

// ---------------------------------------------------------------------------
// fp32 tiled GEMM, PROVEN round-3 geometry: 64x64 tile, BK=32, 4x4 microtile.
// (128x128 regressed: grid fell to 256 blocks = 1 wave/SIMD; this staging
// structure needs >=4 blocks/CU to hide global latency.)
// mode 0: plain A. mode 1: virtual ext row [1, X[t], S[t]] (fallback path).
// ---------------------------------------------------------------------------
#define BM 64
#define BN 64
#define BK 32

__global__ __launch_bounds__(256) void gemm_abt(
    const float* __restrict__ A, int lda,
    const float* __restrict__ B, int ldb,
    float*       __restrict__ C, int ldc,
    int Mdim, int N, int K, int mode,
    const float* __restrict__ X, const float* __restrict__ S)
{
    __shared__ __align__(16) float As[BK][BM + 4];
    __shared__ __align__(16) float Bs[BK][BN + 4];

    const int tid = threadIdx.x;
    const int n0  = blockIdx.x * BN;
    const int m0  = blockIdx.y * BM;
    const int tx  = tid & 15;
    const int ty  = tid >> 4;

    float c[4][4] = {};

    for (int k0 = 0; k0 < K; k0 += BK) {
        #pragma unroll
        for (int p = 0; p < 8; ++p) {
            const int idx = tid + p * 256;
            const int mm  = idx >> 5;
            const int kk  = idx & 31;
            const int gk  = k0 + kk;

            float av = 0.f;
            const int gm = m0 + mm;
            if (gm < Mdim && gk < K) {
                if (mode == 0) {
                    av = A[(size_t)gm * lda + gk];
                } else {
                    if (gk == 0)          av = 1.0f;
                    else if (gk <= IDIM)  av = X[(size_t)gm * IDIM + (gk - 1)];
                    else                  av = S[(size_t)gm * H + (gk - 1 - IDIM)];
                }
            }
            As[kk][mm] = av;

            float bv = 0.f;
            const int gn = n0 + mm;
            if (gn < N && gk < K) bv = B[(size_t)gn * ldb + gk];
            Bs[kk][mm] = bv;
        }
        __syncthreads();

        #pragma unroll
        for (int kk = 0; kk < BK; ++kk) {
            float4 a = *(const float4*)&As[kk][ty * 4];
            float4 b = *(const float4*)&Bs[kk][tx * 4];
            float av[4] = {a.x, a.y, a.z, a.w};
            float bv[4] = {b.x, b.y, b.z, b.w};
            #pragma unroll
            for (int i = 0; i < 4; ++i)
                #pragma unroll
                for (int j = 0; j < 4; ++j)
                    c[i][j] += av[i] * bv[j];
        }
        __syncthreads();
    }

    #pragma unroll
    for (int i = 0; i < 4; ++i) {
        const int gm = m0 + ty * 4 + i;
        if (gm >= Mdim) continue;
        #pragma unroll
        for (int j = 0; j < 4; ++j) {
            const int gn = n0 + tx * 4 + j;
            if (gn < N) C[(size_t)gm * ldc + gn] = c[i][j];
        }
    }
}

// ---------------------------------------------------------------------------
// Phase-2 split-K GEMM, round-15: fp16-pair fdot2 inner loop.
// Same 64x64 tile / 4x4 microtile / split-K=4 as the proven fp32 version,
// but K-pairs packed as half2 in LDS: halves LDS reads (1 b128/operand/kk2
// covers K=2), halves VALU insts (v_dot2_f32_f16 = 2 MAC), halves staging
// writes. fp32 accumulate. Output error ~1e-3 << state-driven absmax.
//   Cp[z][M][N] partial over K-slice z. Grid (N/64, M/64, 4).
// LDS: As16/Bs16 [16 pairs][64+4] uints = 8.7 KB total.
// ---------------------------------------------------------------------------
#define KSLICE 1280   // elements (even: pairs never straddle slices)

__global__ __launch_bounds__(256) void gemm_splitk_h(
    const float* __restrict__ Bw, int ldb,
    float*       __restrict__ Cp,            // 4 partials, stride M*N
    int Mdim, int N, int K,
    const float* __restrict__ X, const float* __restrict__ S)
{
    __shared__ __align__(16) unsigned As16[16][BM + 4];
    __shared__ __align__(16) unsigned Bs16[16][BN + 4];

    const int tid = threadIdx.x;
    const int n0  = blockIdx.x * BN;
    const int m0  = blockIdx.y * BM;
    const int z   = blockIdx.z;
    const int tx  = tid & 15;
    const int ty  = tid >> 4;

    const int kbeg = z * KSLICE;
    const int kend = min(K, kbeg + KSLICE);

    float c[4][4] = {};

    for (int k0 = kbeg; k0 < kend; k0 += BK) {
        const bool pureS = (k0 >= IDIM + 1) && (k0 + BK <= kend) && (k0 + BK <= K);
        const bool pureX = (k0 > 0) && (k0 + BK <= IDIM + 1);
        // stage 64 rows x 16 pairs; 4 p-iters x 256 threads
        #pragma unroll
        for (int p = 0; p < 4; ++p) {
            const int idx = tid + p * 256;
            const int mm  = idx >> 4;          // 0..63
            const int kp  = idx & 15;          // pair 0..15
            const int gk  = k0 + (kp << 1);    // elements gk, gk+1
            const int gm  = m0 + mm;

            float e0 = 0.f, e1 = 0.f;
            if (gm < Mdim) {
                if (pureS) {
                    const float* sp = S + (size_t)gm * H + (gk - 1 - IDIM);
                    e0 = sp[0]; e1 = sp[1];
                } else if (pureX) {
                    const float* xp = X + (size_t)gm * IDIM + (gk - 1);
                    e0 = xp[0]; e1 = xp[1];
                } else {
                    if (gk < kend) {
                        if (gk == 0)          e0 = 1.0f;
                        else if (gk <= IDIM)  e0 = X[(size_t)gm * IDIM + (gk - 1)];
                        else                  e0 = S[(size_t)gm * H + (gk - 1 - IDIM)];
                    }
                    const int g1 = gk + 1;
                    if (g1 < kend) {
                        if (g1 == 0)          e1 = 1.0f;
                        else if (g1 <= IDIM)  e1 = X[(size_t)gm * IDIM + (g1 - 1)];
                        else                  e1 = S[(size_t)gm * H + (g1 - 1 - IDIM)];
                    }
                }
            }
            __half2 ha = __floats2half2_rn(e0, e1);
            As16[kp][mm] = *(unsigned*)&ha;

            float b0 = 0.f, b1 = 0.f;
            const int gn = n0 + mm;
            if (gn < N) {
                if (gk < kend)     b0 = Bw[(size_t)gn * ldb + gk];
                if (gk + 1 < kend) b1 = Bw[(size_t)gn * ldb + gk + 1];
            }
            __half2 hb = __floats2half2_rn(b0, b1);
            Bs16[kp][mm] = *(unsigned*)&hb;
        }
        __syncthreads();

        #pragma unroll
        for (int kp = 0; kp < 16; ++kp) {
            uint4 ua = *(const uint4*)&As16[kp][ty * 4];
            uint4 ub = *(const uint4*)&Bs16[kp][tx * 4];
            unsigned av[4] = {ua.x, ua.y, ua.z, ua.w};
            unsigned bv[4] = {ub.x, ub.y, ub.z, ub.w};
            #pragma unroll
            for (int i = 0; i < 4; ++i)
                #pragma unroll
                for (int j = 0; j < 4; ++j)
                    c[i][j] = fdot2(av[i], bv[j], c[i][j]);
        }
        __syncthreads();
    }

    float* Cz = Cp + (size_t)z * ((size_t)SEQ * IDIM);
    #pragma unroll
    for (int i = 0; i < 4; ++i) {
        const int gm = m0 + ty * 4 + i;
        if (gm >= Mdim) continue;
        #pragma unroll
        for (int j = 0; j < 4; ++j) {
            const int gn = n0 + tx * 4 + j;
            if (gn < N) Cz[(size_t)gm * N + gn] = c[i][j];
        }
    }
}

// out[i] = sum of 4 split-K partials (SEQ*IDIM floats, /4 exact)
__global__ __launch_bounds__(256) void reduce4(
    const float4* __restrict__ p, float4* __restrict__ o, int n4)
{
    const size_t stride = (size_t)SEQ * IDIM / 4;
    for (int i = blockIdx.x * 256 + threadIdx.x; i < n4; i += gridDim.x * 256) {
        float4 a = p[i];
        float4 b = p[i + stride];
        float4 c = p[i + 2 * stride];
        float4 d = p[i + 3 * stride];
        float4 r;
        r.x = a.x + b.x + c.x + d.x;
        r.y = a.y + b.y + c.y + d.y;
        r.z = a.z + b.z + c.z + d.z;
        r.w = a.w + b.w + c.w + d.w;
        o[i] = r;
    }
}

// ---------------------------------------------------------------------------
// Launcher
// ---------------------------------------------------------------------------
extern "C" void kernel_launch(void* const* d_in, const int* in_sizes, int n_in,
                              void* d_out, int out_size, void* d_ws, size_t ws_size,
                              hipStream_t stream) {
    const float* inputs = (const float*)d_in[0];
    // d_in[1] = initial state (zeros) — folded out
    const float* W_ih   = (const float*)d_in[2];
    const float* W_hh   = (const float*)d_in[3];
    const float* W_out  = (const float*)d_in[4];

    float* out    = (float*)d_out;                 // SEQ*IDIM
    float* states = out + (size_t)SEQ * IDIM;      // SEQ*H

    float* pre_in = (float*)d_ws;                  // SEQ*H fp32 (16.4 MB)
    float* cpart  = pre_in + (size_t)SEQ * H;      // 4 * SEQ*IDIM fp32 (14.4 MB)

    const size_t ws_needed = ((size_t)SEQ * H + 4ull * SEQ * IDIM) * sizeof(float);
    const bool   use_splitk = (ws_size >= ws_needed);

    // Tagged s-broadcast scratch in the outputs region of d_out (overwritten
    // by phase 2): 4 slots * 2048 words * 8 B = 64 KB. Harness 0xAA poison
    // gives tag 0xAAAAAAAA, never equal to a live tag (1..1000).
    unsigned long long* part = (unsigned long long*)out;

    (void)hipFuncSetAttribute((const void*)esn_recurrent,
                              hipFuncAttributeMaxDynamicSharedMemorySize,
                              LDS_BYTES);

    // Phase 0: pre_in[t][r] = sum_i X[t][i] * W_ih[r][i]
    gemm_abt<<<dim3(H / BN, (SEQ + BM - 1) / BM), 256, 0, stream>>>(
        inputs, IDIM, W_ih, IDIM, pre_in, H, SEQ, H, IDIM, 0, nullptr, nullptr);

    // Phase 1: persistent sequential recurrence (256 blocks x 1024 threads)
    {
        const float* whh_p = W_hh;
        const float* pin_p = pre_in;
        float* st_p = states;
        unsigned long long* part_p = part;
        void* args[] = { (void*)&whh_p, (void*)&pin_p, (void*)&st_p, (void*)&part_p };
        hipLaunchCooperativeKernel((const void*)esn_recurrent,
                                   dim3(256), dim3(1024), args, LDS_BYTES, stream);
    }

    // Phase 2: outputs[t][i] = sum_k ext[t][k] * W_out[i][k]
    if (use_splitk) {
        gemm_splitk_h<<<dim3((IDIM + BN - 1) / BN, (SEQ + BM - 1) / BM, 4),
                        256, 0, stream>>>(
            W_out, 1 + IDIM + H, cpart, SEQ, IDIM, 1 + IDIM + H, inputs, states);
        const int n4 = SEQ * IDIM / 4;
        reduce4<<<dim3(880), 256, 0, stream>>>(
            (const float4*)cpart, (float4*)out, n4);
    } else {
        gemm_abt<<<dim3((IDIM + BN - 1) / BN, (SEQ + BM - 1) / BM), 256, 0, stream>>>(
            nullptr, 0, W_out, 1 + IDIM + H, out, IDIM,
            SEQ, IDIM, 1 + IDIM + H, 1, inputs, states);
    }
}

// Round 8
// 3018.106 us; speedup vs baseline: 2.0663x; 1.1715x over previous
//
#include <hip/hip_runtime.h>
#include <hip/hip_fp16.h>

#define SEQ  1000
#define IDIM 900
#define H    4096

// LDS carve-up for esn_recurrent (W_hh lives in REGISTERS):
//   s2   : uint[2][2048]  s[t] fp16 pairs, double-buffered = 16384 B
//   redf : float[16][5]   per-(row,colquad) partials       =   320 B
#define LDS_BYTES (16384 + 320)

typedef _Float16 h2_t __attribute__((ext_vector_type(2)));

__device__ __forceinline__ float fdot2(unsigned a, unsigned b, float c) {
#if __has_builtin(__builtin_amdgcn_fdot2)
    return __builtin_amdgcn_fdot2(__builtin_bit_cast(h2_t, a),
                                  __builtin_bit_cast(h2_t, b), c, false);
#else
    h2_t ha = __builtin_bit_cast(h2_t, a);
    h2_t hb = __builtin_bit_cast(h2_t, b);
    return c + (float)ha.x * (float)hb.x + (float)ha.y * (float)hb.y;
#endif
}

__device__ __forceinline__ float tanh_fast(float x) {
    float ax = __builtin_fabsf(x);
    float e  = __expf(-2.0f * ax);
    float t  = (1.0f - e) / (1.0f + e);
    return __builtin_copysignf(t, x);
}

// Bank swizzle on s2 dword indices: XOR bits [4:2] with bits [7:5].
__device__ __forceinline__ int swz2(int d) { return d ^ (((d >> 5) & 7) << 2); }

__device__ __forceinline__ uint4 pack8(float4 f0, float4 f1) {
    __half2 p; uint4 u;
    p = __floats2half2_rn(f0.x, f0.y); u.x = *(unsigned*)&p;
    p = __floats2half2_rn(f0.z, f0.w); u.y = *(unsigned*)&p;
    p = __floats2half2_rn(f1.x, f1.y); u.z = *(unsigned*)&p;
    p = __floats2half2_rn(f1.z, f1.w); u.w = *(unsigned*)&p;
    return u;
}

// ---------------------------------------------------------------------------
// Persistent recurrent kernel, round-16: round-9 structure (proven, bit-
// stable 2960 us x3 runs) + PHASE-0 FUSION. The W_ih x[t+1] contribution for
// a block's 16 rows is only 16 fp32 FMAs/thread; x[t+1] (3.6 KB, L3
// broadcast) is s-independent, so its load issues BEFORE the poll and the
// dot computes in the poll-wait slack. Accumulators a0..a3 START from the
// x-dot instead of 0 -> the existing butterfly+redf reduction sums
// W_ih*x + W_hh*s in one pass. pre_in, the phase-0 GEMM, and the pv path
// are deleted. s[0] comes from a peeled iteration (W_hh part absent).
// Poll/publish/barrier machinery BYTE-IDENTICAL to round 9 (rounds 11/13
// taught: never touch the tail). All-fp32 x-path: numerics = summation
// reorder only.
// Thread -> x-slot map: slot = 64*qd + lane covers x cols [4*slot, +4),
// rows 4h..4h+3. The 4 qd-waves of row-group h cover slots 0..255 = cols
// 0..1023 (guard at 900) exactly once; butterfly sums 64 lanes, redf sums
// 4 qd -> full 900-col dot per row.
// ---------------------------------------------------------------------------
__global__ __launch_bounds__(1024, 4) void esn_recurrent(
    const float* __restrict__ Whh,            // H*H row-major fp32
    const float* __restrict__ Wih,            // H*IDIM row-major fp32
    const float* __restrict__ X,              // SEQ*IDIM fp32 inputs
    float*       __restrict__ states,         // SEQ*H (inside d_out)
    unsigned long long* __restrict__ part)    // 4*2048 tagged words (d_out scratch)
{
    extern __shared__ char smem[];
    unsigned* s2   = (unsigned*)smem;               // [2][2048] swizzled
    float*    redf = (float*)(smem + 16384);        // [16][5]

    const int B    = blockIdx.x;       // owns rows [16B, +16)
    const int tid  = threadIdx.x;
    const int wave = tid >> 6;         // 0..15
    const int lane = tid & 63;
    const int h    = wave >> 2;        // row quad: rows 4h..4h+3 (of my 16)
    const int qd   = wave & 3;         // col quad: cols [1024qd, +1024)

    const int c0   = ((qd << 6) + lane) << 2;   // x-col base of my slot
    const bool sOK = (c0 < IDIM);               // c0 <= 896 -> cols c0..c0+3 valid

    // ---- load my 4x16 W_hh patch into registers (fp16 pairs, once) ----
    uint4 wa0, wb0, wa1, wb1, wa2, wb2, wa3, wb3;
    {
        const float* wsrc = Whh + ((size_t)((B << 4) + (h << 2))) * H
                          + (qd << 10) + (lane << 4);
        const float4* r0 = (const float4*)(wsrc);
        const float4* r1 = (const float4*)(wsrc + H);
        const float4* r2 = (const float4*)(wsrc + 2 * H);
        const float4* r3 = (const float4*)(wsrc + 3 * H);
        wa0 = pack8(r0[0], r0[1]); wb0 = pack8(r0[2], r0[3]);
        wa1 = pack8(r1[0], r1[1]); wb1 = pack8(r1[2], r1[3]);
        wa2 = pack8(r2[0], r2[1]); wb2 = pack8(r2[2], r2[3]);
        wa3 = pack8(r3[0], r3[1]); wb3 = pack8(r3[2], r3[3]);
    }
    // ---- load my 4x4 W_ih patch (fp32, once) ----
    float4 wi0 = {}, wi1 = {}, wi2 = {}, wi3 = {};
    if (sOK) {
        const float* wis = Wih + (size_t)((B << 4) + (h << 2)) * IDIM + c0;
        wi0 = *(const float4*)(wis);
        wi1 = *(const float4*)(wis + IDIM);
        wi2 = *(const float4*)(wis + 2 * IDIM);
        wi3 = *(const float4*)(wis + 3 * IDIM);
    }

    // ---- peeled t = -1: s[0] = tanh(W_ih x[0]) through the same reducer ----
    {
        float4 xv = {};
        if (sOK) xv = *(const float4*)(X + c0);
        float a0 = fmaf(wi0.w, xv.w, fmaf(wi0.z, xv.z, fmaf(wi0.y, xv.y, wi0.x * xv.x)));
        float a1 = fmaf(wi1.w, xv.w, fmaf(wi1.z, xv.z, fmaf(wi1.y, xv.y, wi1.x * xv.x)));
        float a2 = fmaf(wi2.w, xv.w, fmaf(wi2.z, xv.z, fmaf(wi2.y, xv.y, wi2.x * xv.x)));
        float a3 = fmaf(wi3.w, xv.w, fmaf(wi3.z, xv.z, fmaf(wi3.y, xv.y, wi3.x * xv.x)));

        float y0 = (lane & 1) ? a0 : a1;
        float x  = (lane & 1) ? a1 : a0;
        x += __shfl_xor(y0, 1);
        float y1 = (lane & 1) ? a2 : a3;
        float z  = (lane & 1) ? a3 : a2;
        z += __shfl_xor(y1, 1);
        float y2 = (lane & 2) ? x : z;
        float u  = (lane & 2) ? z : x;
        u += __shfl_xor(y2, 2);
        u += __shfl_xor(u, 4);
        u += __shfl_xor(u, 8);
        u += __shfl_xor(u, 16);
        u += __shfl_xor(u, 32);

        if (lane < 4) redf[((h << 2) + lane) * 5 + qd] = u;
        __syncthreads();

        if (wave == 0) {
            float sf = 0.f;
            if (lane < 16) {
                const float* rf = redf + lane * 5;
                sf = tanh_fast(rf[0] + rf[1] + rf[2] + rf[3]);
                states[(B << 4) + lane] = sf;
            }
            float a = __shfl(sf, lane << 1);
            float b = __shfl(sf, (lane << 1) + 1);
            if (lane < 8) {
                __half2 p = __floats2half2_rn(a, b);
                unsigned long long wrd = (1ull << 32)
                                       | (unsigned long long)(*(unsigned*)&p);
                __hip_atomic_store(part + (B << 3) + lane, wrd,
                                   __ATOMIC_RELAXED, __HIP_MEMORY_SCOPE_AGENT);
            }
        }
    }

    for (int t = 0; t < SEQ - 1; ++t) {
        // issue x[t+1] slice load BEFORE the poll; arrives during the spin
        float4 xv = {};
        if (sOK) xv = *(const float4*)(X + (size_t)(t + 1) * IDIM + c0);

        // ---- A. poll s[t] (slot t&3, tag t+1); thread owns words 2tid,2tid+1 ----
        {
            const unsigned long long* pb = part + ((size_t)(t & 3) << 11) + (tid << 1);
            const unsigned want = (unsigned)(t + 1);
            unsigned long long v0, v1;
            for (;;) {
                v0 = __hip_atomic_load(pb,     __ATOMIC_RELAXED, __HIP_MEMORY_SCOPE_AGENT);
                v1 = __hip_atomic_load(pb + 1, __ATOMIC_RELAXED, __HIP_MEMORY_SCOPE_AGENT);
                if ((unsigned)(v0 >> 32) == want && (unsigned)(v1 >> 32) == want) break;
                __builtin_amdgcn_s_sleep(1);
            }
            uint2 w; w.x = (unsigned)v0; w.y = (unsigned)v1;
            *(uint2*)(s2 + ((t & 1) << 11) + swz2(tid << 1)) = w;
        }
        __syncthreads();   // barrier A

        // ---- B. accumulators start from the W_ih x-dot (phase-0 fusion) ----
        float a0 = fmaf(wi0.w, xv.w, fmaf(wi0.z, xv.z, fmaf(wi0.y, xv.y, wi0.x * xv.x)));
        float a1 = fmaf(wi1.w, xv.w, fmaf(wi1.z, xv.z, fmaf(wi1.y, xv.y, wi1.x * xv.x)));
        float a2 = fmaf(wi2.w, xv.w, fmaf(wi2.z, xv.z, fmaf(wi2.y, xv.y, wi2.x * xv.x)));
        float a3 = fmaf(wi3.w, xv.w, fmaf(wi3.z, xv.z, fmaf(wi3.y, xv.y, wi3.x * xv.x)));

        // rows 4h..4h+3 x s-cols [1024qd + 16*lane, +16)
        const unsigned* sb = s2 + ((t & 1) << 11);
        const int cb = (qd << 9) + (lane << 3);
        uint4 sa = *(const uint4*)(sb + swz2(cb));
        uint4 sc = *(const uint4*)(sb + swz2(cb + 4));

        a0 = fdot2(wa0.x, sa.x, a0); a0 = fdot2(wa0.y, sa.y, a0);
        a0 = fdot2(wa0.z, sa.z, a0); a0 = fdot2(wa0.w, sa.w, a0);
        a0 = fdot2(wb0.x, sc.x, a0); a0 = fdot2(wb0.y, sc.y, a0);
        a0 = fdot2(wb0.z, sc.z, a0); a0 = fdot2(wb0.w, sc.w, a0);
        a1 = fdot2(wa1.x, sa.x, a1); a1 = fdot2(wa1.y, sa.y, a1);
        a1 = fdot2(wa1.z, sa.z, a1); a1 = fdot2(wa1.w, sa.w, a1);
        a1 = fdot2(wb1.x, sc.x, a1); a1 = fdot2(wb1.y, sc.y, a1);
        a1 = fdot2(wb1.z, sc.z, a1); a1 = fdot2(wb1.w, sc.w, a1);
        a2 = fdot2(wa2.x, sa.x, a2); a2 = fdot2(wa2.y, sa.y, a2);
        a2 = fdot2(wa2.z, sa.z, a2); a2 = fdot2(wa2.w, sa.w, a2);
        a2 = fdot2(wb2.x, sc.x, a2); a2 = fdot2(wb2.y, sc.y, a2);
        a2 = fdot2(wb2.z, sc.z, a2); a2 = fdot2(wb2.w, sc.w, a2);
        a3 = fdot2(wa3.x, sa.x, a3); a3 = fdot2(wa3.y, sa.y, a3);
        a3 = fdot2(wa3.z, sa.z, a3); a3 = fdot2(wa3.w, sa.w, a3);
        a3 = fdot2(wb3.x, sc.x, a3); a3 = fdot2(wb3.y, sc.y, a3);
        a3 = fdot2(wb3.z, sc.z, a3); a3 = fdot2(wb3.w, sc.w, a3);

        // ---- merged butterfly: 7 shuffles ----
        float y0 = (lane & 1) ? a0 : a1;
        float x  = (lane & 1) ? a1 : a0;
        x += __shfl_xor(y0, 1);
        float y1 = (lane & 1) ? a2 : a3;
        float z  = (lane & 1) ? a3 : a2;
        z += __shfl_xor(y1, 1);
        float y2 = (lane & 2) ? x : z;
        float u  = (lane & 2) ? z : x;
        u += __shfl_xor(y2, 2);
        u += __shfl_xor(u, 4);
        u += __shfl_xor(u, 8);
        u += __shfl_xor(u, 16);
        u += __shfl_xor(u, 32);

        if (lane < 4) redf[((h << 2) + lane) * 5 + qd] = u;
        __syncthreads();   // barrier B

        // ---- C. finalize (wave 0 only) ----
        if (wave == 0) {
            float sf = 0.f;
            if (lane < 16) {
                const float* rf = redf + lane * 5;
                sf = tanh_fast(rf[0] + rf[1] + rf[2] + rf[3]);
                states[(size_t)(t + 1) * H + (B << 4) + lane] = sf;
            }
            float a = __shfl(sf, lane << 1);
            float b = __shfl(sf, (lane << 1) + 1);
            if (lane < 8) {
                __half2 p = __floats2half2_rn(a, b);
                unsigned long long wrd = ((unsigned long long)(unsigned)(t + 2) << 32)
                                       | (unsigned long long)(*(unsigned*)&p);
                __hip_atomic_store(part + ((size_t)((t + 1) & 3) << 11) + (B << 3) + lane,
                                   wrd, __ATOMIC_RELAXED, __HIP_MEMORY_SCOPE_AGENT);
            }
        }
    }
}

// ---------------------------------------------------------------------------
// fp32 tiled GEMM (fallback path only): 64x64 tile, BK=32, 4x4 microtile.
// mode 1: virtual ext row [1, X[t], S[t]].
// ---------------------------------------------------------------------------
#define BM 64
#define BN 64
#define BK 32

__global__ __launch_bounds__(256) void gemm_abt(
    const float* __restrict__ A, int lda,
    const float* __restrict__ B, int ldb,
    float*       __restrict__ C, int ldc,
    int Mdim, int N, int K, int mode,
    const float* __restrict__ X, const float* __restrict__ S)
{
    __shared__ __align__(16) float As[BK][BM + 4];
    __shared__ __align__(16) float Bs[BK][BN + 4];

    const int tid = threadIdx.x;
    const int n0  = blockIdx.x * BN;
    const int m0  = blockIdx.y * BM;
    const int tx  = tid & 15;
    const int ty  = tid >> 4;

    float c[4][4] = {};

    for (int k0 = 0; k0 < K; k0 += BK) {
        #pragma unroll
        for (int p = 0; p < 8; ++p) {
            const int idx = tid + p * 256;
            const int mm  = idx >> 5;
            const int kk  = idx & 31;
            const int gk  = k0 + kk;

            float av = 0.f;
            const int gm = m0 + mm;
            if (gm < Mdim && gk < K) {
                if (mode == 0) {
                    av = A[(size_t)gm * lda + gk];
                } else {
                    if (gk == 0)          av = 1.0f;
                    else if (gk <= IDIM)  av = X[(size_t)gm * IDIM + (gk - 1)];
                    else                  av = S[(size_t)gm * H + (gk - 1 - IDIM)];
                }
            }
            As[kk][mm] = av;

            float bv = 0.f;
            const int gn = n0 + mm;
            if (gn < N && gk < K) bv = B[(size_t)gn * ldb + gk];
            Bs[kk][mm] = bv;
        }
        __syncthreads();

        #pragma unroll
        for (int kk = 0; kk < BK; ++kk) {
            float4 a = *(const float4*)&As[kk][ty * 4];
            float4 b = *(const float4*)&Bs[kk][tx * 4];
            float av[4] = {a.x, a.y, a.z, a.w};
            float bv[4] = {b.x, b.y, b.z, b.w};
            #pragma unroll
            for (int i = 0; i < 4; ++i)
                #pragma unroll
                for (int j = 0; j < 4; ++j)
                    c[i][j] += av[i] * bv[j];
        }
        __syncthreads();
    }

    #pragma unroll
    for (int i = 0; i < 4; ++i) {
        const int gm = m0 + ty * 4 + i;
        if (gm >= Mdim) continue;
        #pragma unroll
        for (int j = 0; j < 4; ++j) {
            const int gn = n0 + tx * 4 + j;
            if (gn < N) C[(size_t)gm * ldc + gn] = c[i][j];
        }
    }
}

// ---------------------------------------------------------------------------
// Phase-2 split-K GEMM (proven round-15): fp16-pair fdot2 inner loop.
//   Cp[z][M][N] partial over K-slice z. Grid (N/64, M/64, 4).
// ---------------------------------------------------------------------------
#define KSLICE 1280   // elements (even: pairs never straddle slices)

__global__ __launch_bounds__(256) void gemm_splitk_h(
    const float* __restrict__ Bw, int ldb,
    float*       __restrict__ Cp,            // 4 partials, stride M*N
    int Mdim, int N, int K,
    const float* __restrict__ X, const float* __restrict__ S)
{
    __shared__ __align__(16) unsigned As16[16][BM + 4];
    __shared__ __align__(16) unsigned Bs16[16][BN + 4];

    const int tid = threadIdx.x;
    const int n0  = blockIdx.x * BN;
    const int m0  = blockIdx.y * BM;
    const int z   = blockIdx.z;
    const int tx  = tid & 15;
    const int ty  = tid >> 4;

    const int kbeg = z * KSLICE;
    const int kend = min(K, kbeg + KSLICE);

    float c[4][4] = {};

    for (int k0 = kbeg; k0 < kend; k0 += BK) {
        const bool pureS = (k0 >= IDIM + 1) && (k0 + BK <= kend) && (k0 + BK <= K);
        const bool pureX = (k0 > 0) && (k0 + BK <= IDIM + 1);
        #pragma unroll
        for (int p = 0; p < 4; ++p) {
            const int idx = tid + p * 256;
            const int mm  = idx >> 4;          // 0..63
            const int kp  = idx & 15;          // pair 0..15
            const int gk  = k0 + (kp << 1);    // elements gk, gk+1
            const int gm  = m0 + mm;

            float e0 = 0.f, e1 = 0.f;
            if (gm < Mdim) {
                if (pureS) {
                    const float* sp = S + (size_t)gm * H + (gk - 1 - IDIM);
                    e0 = sp[0]; e1 = sp[1];
                } else if (pureX) {
                    const float* xp = X + (size_t)gm * IDIM + (gk - 1);
                    e0 = xp[0]; e1 = xp[1];
                } else {
                    if (gk < kend) {
                        if (gk == 0)          e0 = 1.0f;
                        else if (gk <= IDIM)  e0 = X[(size_t)gm * IDIM + (gk - 1)];
                        else                  e0 = S[(size_t)gm * H + (gk - 1 - IDIM)];
                    }
                    const int g1 = gk + 1;
                    if (g1 < kend) {
                        if (g1 == 0)          e1 = 1.0f;
                        else if (g1 <= IDIM)  e1 = X[(size_t)gm * IDIM + (g1 - 1)];
                        else                  e1 = S[(size_t)gm * H + (g1 - 1 - IDIM)];
                    }
                }
            }
            __half2 ha = __floats2half2_rn(e0, e1);
            As16[kp][mm] = *(unsigned*)&ha;

            float b0 = 0.f, b1 = 0.f;
            const int gn = n0 + mm;
            if (gn < N) {
                if (gk < kend)     b0 = Bw[(size_t)gn * ldb + gk];
                if (gk + 1 < kend) b1 = Bw[(size_t)gn * ldb + gk + 1];
            }
            __half2 hb = __floats2half2_rn(b0, b1);
            Bs16[kp][mm] = *(unsigned*)&hb;
        }
        __syncthreads();

        #pragma unroll
        for (int kp = 0; kp < 16; ++kp) {
            uint4 ua = *(const uint4*)&As16[kp][ty * 4];
            uint4 ub = *(const uint4*)&Bs16[kp][tx * 4];
            unsigned av[4] = {ua.x, ua.y, ua.z, ua.w};
            unsigned bv[4] = {ub.x, ub.y, ub.z, ub.w};
            #pragma unroll
            for (int i = 0; i < 4; ++i)
                #pragma unroll
                for (int j = 0; j < 4; ++j)
                    c[i][j] = fdot2(av[i], bv[j], c[i][j]);
        }
        __syncthreads();
    }

    float* Cz = Cp + (size_t)z * ((size_t)SEQ * IDIM);
    #pragma unroll
    for (int i = 0; i < 4; ++i) {
        const int gm = m0 + ty * 4 + i;
        if (gm >= Mdim) continue;
        #pragma unroll
        for (int j = 0; j < 4; ++j) {
            const int gn = n0 + tx * 4 + j;
            if (gn < N) Cz[(size_t)gm * N + gn] = c[i][j];
        }
    }
}

// out[i] = sum of 4 split-K partials (SEQ*IDIM floats, /4 exact)
__global__ __launch_bounds__(256) void reduce4(
    const float4* __restrict__ p, float4* __restrict__ o, int n4)
{
    const size_t stride = (size_t)SEQ * IDIM / 4;
    for (int i = blockIdx.x * 256 + threadIdx.x; i < n4; i += gridDim.x * 256) {
        float4 a = p[i];
        float4 b = p[i + stride];
        float4 c = p[i + 2 * stride];
        float4 d = p[i + 3 * stride];
        float4 r;
        r.x = a.x + b.x + c.x + d.x;
        r.y = a.y + b.y + c.y + d.y;
        r.z = a.z + b.z + c.z + d.z;
        r.w = a.w + b.w + c.w + d.w;
        o[i] = r;
    }
}

// ---------------------------------------------------------------------------
// Launcher
// ---------------------------------------------------------------------------
extern "C" void kernel_launch(void* const* d_in, const int* in_sizes, int n_in,
                              void* d_out, int out_size, void* d_ws, size_t ws_size,
                              hipStream_t stream) {
    const float* inputs = (const float*)d_in[0];
    // d_in[1] = initial state (zeros) — folded out
    const float* W_ih   = (const float*)d_in[2];
    const float* W_hh   = (const float*)d_in[3];
    const float* W_out  = (const float*)d_in[4];

    float* out    = (float*)d_out;                 // SEQ*IDIM
    float* states = out + (size_t)SEQ * IDIM;      // SEQ*H

    float* cpart  = (float*)d_ws;                  // 4 * SEQ*IDIM fp32 (14.4 MB)

    const size_t ws_needed = 4ull * SEQ * IDIM * sizeof(float);
    const bool   use_splitk = (ws_size >= ws_needed);

    // Tagged s-broadcast scratch in the outputs region of d_out (overwritten
    // by phase 2): 4 slots * 2048 words * 8 B = 64 KB. Harness 0xAA poison
    // gives tag 0xAAAAAAAA, never equal to a live tag (1..1000).
    unsigned long long* part = (unsigned long long*)out;

    (void)hipFuncSetAttribute((const void*)esn_recurrent,
                              hipFuncAttributeMaxDynamicSharedMemorySize,
                              LDS_BYTES);

    // Phase 1: persistent sequential recurrence with fused W_ih*x
    // (256 blocks x 1024 threads; phase-0 GEMM deleted)
    {
        const float* whh_p = W_hh;
        const float* wih_p = W_ih;
        const float* x_p   = inputs;
        float* st_p = states;
        unsigned long long* part_p = part;
        void* args[] = { (void*)&whh_p, (void*)&wih_p, (void*)&x_p,
                         (void*)&st_p, (void*)&part_p };
        hipLaunchCooperativeKernel((const void*)esn_recurrent,
                                   dim3(256), dim3(1024), args, LDS_BYTES, stream);
    }

    // Phase 2: outputs[t][i] = sum_k ext[t][k] * W_out[i][k]
    if (use_splitk) {
        gemm_splitk_h<<<dim3((IDIM + BN - 1) / BN, (SEQ + BM - 1) / BM, 4),
                        256, 0, stream>>>(
            W_out, 1 + IDIM + H, cpart, SEQ, IDIM, 1 + IDIM + H, inputs, states);
        const int n4 = SEQ * IDIM / 4;
        reduce4<<<dim3(880), 256, 0, stream>>>(
            (const float4*)cpart, (float4*)out, n4);
    } else {
        gemm_abt<<<dim3((IDIM + BN - 1) / BN, (SEQ + BM - 1) / BM), 256, 0, stream>>>(
            nullptr, 0, W_out, 1 + IDIM + H, out, IDIM,
            SEQ, IDIM, 1 + IDIM + H, 1, inputs, states);
    }
}